// Round 15
// baseline (1011.573 us; speedup 1.0000x reference)
//
#include <hip/hip_runtime.h>
#include <hip/hip_bf16.h>
#include <stdint.h>

typedef unsigned short u16;
typedef unsigned int u32;
typedef unsigned long long u64;
typedef __attribute__((ext_vector_type(4))) float f32x4;
typedef __attribute__((ext_vector_type(8))) short s16x8;
typedef __attribute__((ext_vector_type(4))) unsigned int u32x4;

#define AT_LD(p)    __hip_atomic_load((p), __ATOMIC_RELAXED, __HIP_MEMORY_SCOPE_AGENT)
#define AT_ST(p, v) __hip_atomic_store((p), (v), __ATOMIC_RELAXED, __HIP_MEMORY_SCOPE_AGENT)
#define AT_FAA(p)   __hip_atomic_fetch_add((p), 1u, __ATOMIC_RELAXED, __HIP_MEMORY_SCOPE_AGENT)

// ---------- helpers ----------

static __device__ __forceinline__ u16 f2bf(float f) {
  union { float f; unsigned u; } v; v.f = f;
  unsigned r = v.u + 0x7FFFu + ((v.u >> 16) & 1u);
  return (u16)(r >> 16);
}

static __device__ __forceinline__ float bf2f(u16 b) {
  union { unsigned u; float f; } v; v.u = ((u32)b) << 16;
  return v.f;
}

static __device__ __forceinline__ void gload_lds16(const void* g, void* l) {
  __builtin_amdgcn_global_load_lds(
      (const __attribute__((address_space(1))) unsigned int*)(uintptr_t)g,
      (__attribute__((address_space(3))) unsigned int*)(uintptr_t)l,
      16, 0, 0);
}

// ---------- pre-pass kernels ----------

__global__ void embed_kernel(const int* __restrict__ inputs,
                             const float* __restrict__ emb,
                             u16* __restrict__ xbf) {
  int i = blockIdx.x * 256 + threadIdx.x;   // 131072 threads
  int row = i >> 6;
  int e0 = (i & 63) << 3;
  int tok = inputs[row];
  const float* src = emb + (size_t)tok * 512 + e0;
  s16x8 o;
#pragma unroll
  for (int j = 0; j < 8; ++j) o[j] = (short)f2bf(src[j]);
  *(s16x8*)(xbf + (size_t)row * 512 + e0) = o;
}

// bit-pack mask: maskb[b*2+h] bit j = (inputs[b*128 + h*64 + j] != 0)
__global__ void mask_kernel(const int* __restrict__ inputs, u64* __restrict__ mb) {
  int t = threadIdx.x;
  if (t < 32) {
    int b = t >> 1, h = t & 1;
    u64 m = 0;
    for (int j = 0; j < 64; ++j)
      m |= (u64)(inputs[b * 128 + h * 64 + j] != 0) << j;
    mb[t] = m;
  }
}

// Wt[n][k] = bf16(W[k][n]); K,N multiples of 32
__global__ void transpose_bf16(const float* __restrict__ W, u16* __restrict__ Wt,
                               int K, int N) {
  __shared__ float t[32][33];
  int ntn = N >> 5;
  int tn = blockIdx.x % ntn, tk = blockIdx.x / ntn;
  int n0 = tn << 5, k0 = tk << 5;
  int tx = threadIdx.x & 31, ty = threadIdx.x >> 5;  // ty 0..7
#pragma unroll
  for (int j = 0; j < 4; ++j) {
    int k = ty * 4 + j;
    t[k][tx] = W[(size_t)(k0 + k) * N + n0 + tx];
  }
  __syncthreads();
#pragma unroll
  for (int j = 0; j < 4; ++j) {
    int n = ty * 4 + j;
    Wt[(size_t)(n0 + n) * K + k0 + tx] = f2bf(t[tx][n]);
  }
}

// ---------- m97-style bf16 GEMM, 128x128 tile, BK=32 ----------
// MODE 0: C=f32, store acc+bias          (xg)
// MODE 1: C=bf16, store relu(acc+bias)   (d1)
// MODE 2: C=f32, store exp(acc+bias), atomicAdd row sums (fallback path)
template <int MODE>
__global__ __launch_bounds__(256)
void gemm_bf16(const u16* __restrict__ A, const u16* __restrict__ Bt,
               const float* __restrict__ bias, void* __restrict__ Cptr,
               float* __restrict__ rowsum, int M, int N, int K) {
  (void)M;
  __shared__ u16 sA[128 * 32];
  __shared__ u16 sB[128 * 32];
  const int nbn = N >> 7;
  const int nwg = gridDim.x;
  int bid = blockIdx.x;
  int q = nwg >> 3;                         // grids are multiples of 8
  int swz = (bid & 7) * q + (bid >> 3);     // XCD-aware swizzle (bijective)
  int bm = swz / nbn, bn = swz % nbn;
  const int brow = bm << 7, bcol = bn << 7;

  const int tid = threadIdx.x;
  const int lane = tid & 63;
  const int wv = tid >> 6;
  const int wr = (wv >> 1) * 64, wc = (wv & 1) * 64;
  const int ln = lane & 15, kh = lane >> 4;

  const int srow = tid >> 2;                // 0..63
  const int kch = (tid & 3) << 3;           // 0,8,16,24 (elements)

  f32x4 acc[4][4] = {};

  const int nk = K >> 5;
  const u16* Abase = A + (size_t)(brow + srow) * K + kch;
  const u16* Bbase = Bt + (size_t)(bcol + srow) * K + kch;
  const size_t rstride = (size_t)64 * K;
  u16* lA = sA + srow * 32 + kch;
  u16* lB = sB + srow * 32 + kch;

  for (int kt = 0; kt < nk; ++kt) {
    const int k0 = kt << 5;
    gload_lds16(Abase + k0, lA);
    gload_lds16(Abase + rstride + k0, lA + 64 * 32);
    gload_lds16(Bbase + k0, lB);
    gload_lds16(Bbase + rstride + k0, lB + 64 * 32);
    __syncthreads();
    s16x8 aF[4], bF[4];
#pragma unroll
    for (int m = 0; m < 4; ++m)
      aF[m] = *(const s16x8*)(sA + (wr + m * 16 + ln) * 32 + kh * 8);
#pragma unroll
    for (int n = 0; n < 4; ++n)
      bF[n] = *(const s16x8*)(sB + (wc + n * 16 + ln) * 32 + kh * 8);
#pragma unroll
    for (int m = 0; m < 4; ++m)
#pragma unroll
      for (int n = 0; n < 4; ++n)
        acc[m][n] = __builtin_amdgcn_mfma_f32_16x16x32_bf16(aF[m], bF[n], acc[m][n], 0, 0, 0);
    __syncthreads();
  }

  const int browq = brow + wr;
  const int bcolq = bcol + wc;

  if (MODE == 1) {
    u16* O = (u16*)Cptr;
#pragma unroll
    for (int n = 0; n < 4; ++n) {
      int gcol = bcolq + n * 16 + ln;
      float bv = bias[gcol];
#pragma unroll
      for (int m = 0; m < 4; ++m)
#pragma unroll
        for (int r = 0; r < 4; ++r) {
          int grow = browq + m * 16 + kh * 4 + r;
          float v = fmaxf(acc[m][n][r] + bv, 0.f);
          O[(size_t)grow * N + gcol] = f2bf(v);
        }
    }
  } else {
    float* O = (float*)Cptr;
    float rs[4][4] = {};
#pragma unroll
    for (int n = 0; n < 4; ++n) {
      int gcol = bcolq + n * 16 + ln;
      float bv = bias[gcol];
#pragma unroll
      for (int m = 0; m < 4; ++m)
#pragma unroll
        for (int r = 0; r < 4; ++r) {
          int grow = browq + m * 16 + kh * 4 + r;
          float v = acc[m][n][r] + bv;
          if (MODE == 2) { v = __expf(v); rs[m][r] += v; }
          O[(size_t)grow * N + gcol] = v;
        }
    }
    if (MODE == 2) {
#pragma unroll
      for (int m = 0; m < 4; ++m)
#pragma unroll
        for (int r = 0; r < 4; ++r) {
          float v = rs[m][r];
          v += __shfl_xor(v, 1);
          v += __shfl_xor(v, 2);
          v += __shfl_xor(v, 4);
          v += __shfl_xor(v, 8);
          if (ln == 0) atomicAdd(&rowsum[browq + m * 16 + kh * 4 + r], v);
        }
    }
  }
}

// ---------- 256x256-tile logits GEMM, counted-vmcnt 4-buffer pipeline ----------
__global__ __launch_bounds__(512, 1)
void gemm256_exp(const u16* __restrict__ A, const u16* __restrict__ Bt,
                 const float* __restrict__ bias, u16* __restrict__ O,
                 float* __restrict__ rowsum, int M, int N, int K) {
  (void)M;
  __shared__ char lds[131072];              // 4 bufs x 32KB
  const int nbn = N >> 8;                   // 125
  const int nwg = gridDim.x;                // 1000 (multiple of 8)
  int bid = blockIdx.x;
  int q = nwg >> 3;
  int swz = (bid & 7) * q + (bid >> 3);     // XCD swizzle (bijective)
  int bm = swz / nbn, bn = swz % nbn;
  const int brow = bm << 8, bcol = bn << 8;

  const int tid = threadIdx.x;
  const int lane = tid & 63;
  const int wv = tid >> 6;                  // 0..7
  const int wm = wv >> 2, wn = wv & 3;
  const int ln = lane & 15, kh = lane >> 4;

  const int nk = K >> 5;                    // 32

  const u16* sbase[4];
#pragma unroll
  for (int j = 0; j < 4; ++j) {
    int cc = (j & 1) * 512 + wv * 64 + lane;
    int row = cc >> 2, pcol = cc & 3;
    int lcol = pcol ^ ((row >> 1) & 3);
    sbase[j] = (j < 2 ? A + (size_t)(brow + row) * K
                      : Bt + (size_t)(bcol + row) * K) + lcol * 8;
  }

#define STAGE256(kt, buf)                                                  \
  {                                                                        \
    char* lb = lds + (buf) * 32768 + wv * 1024;                            \
    _Pragma("unroll")                                                      \
    for (int j = 0; j < 4; ++j)                                            \
      gload_lds16(sbase[j] + (kt) * 32, lb + j * 8192);                    \
  }

  f32x4 acc[8][4] = {};

  STAGE256(0, 0);
  STAGE256(1, 1);
  asm volatile("s_waitcnt vmcnt(4)" ::: "memory");   // tile 0 landed
  __syncthreads();

  const char* Ab = lds + (size_t)(wm * 128) * 64;
  const char* Bb = lds + 16384 + (size_t)(wn * 64) * 64;
  const int cswz = (kh ^ ((ln >> 1) & 3)) * 16 + ln * 64;

  for (int t = 0; t < nk; ++t) {
    const int boff = (t & 3) * 32768;
    if (t + 2 < nk) STAGE256(t + 2, (t + 2) & 3);
    s16x8 aF[8], bF[4];
#pragma unroll
    for (int m = 0; m < 8; ++m)
      aF[m] = *(const s16x8*)(Ab + boff + m * 1024 + cswz);
#pragma unroll
    for (int n = 0; n < 4; ++n)
      bF[n] = *(const s16x8*)(Bb + boff + n * 1024 + cswz);
    __builtin_amdgcn_s_setprio(1);
#pragma unroll
    for (int m = 0; m < 8; ++m)
#pragma unroll
      for (int n = 0; n < 4; ++n)
        acc[m][n] = __builtin_amdgcn_mfma_f32_16x16x32_bf16(aF[m], bF[n], acc[m][n], 0, 0, 0);
    __builtin_amdgcn_s_setprio(0);
    if (t + 2 < nk)
      asm volatile("s_waitcnt vmcnt(4)" ::: "memory");   // tile t+1 landed
    else
      asm volatile("s_waitcnt vmcnt(0)" ::: "memory");   // drain tail
    if (t < nk - 1) __syncthreads();
  }

  // ---- fused softmax-exp epilogue ----
  const int browq = brow + wm * 128;
  const int bcolq = bcol + wn * 64;
  float rs[8][4] = {};
#pragma unroll
  for (int n = 0; n < 4; ++n) {
    int gcol = bcolq + n * 16 + ln;
    float bv = bias[gcol];
#pragma unroll
    for (int m = 0; m < 8; ++m)
#pragma unroll
      for (int r = 0; r < 4; ++r) {
        float v = __expf(acc[m][n][r] + bv);
        rs[m][r] += v;
        O[(size_t)(browq + m * 16 + kh * 4 + r) * N + gcol] = f2bf(v);
      }
  }
#pragma unroll
  for (int m = 0; m < 8; ++m)
#pragma unroll
    for (int r = 0; r < 4; ++r) {
      float v = rs[m][r];
      v += __shfl_xor(v, 1);
      v += __shfl_xor(v, 2);
      v += __shfl_xor(v, 4);
      v += __shfl_xor(v, 8);
      if (ln == 0) atomicAdd(&rowsum[browq + m * 16 + kh * 4 + r], v);
    }
#undef STAGE256
}

// ---------- persistent LSTM: 32 WGs x 512 threads, K-quartered waves ----------
// r14 falsified the B-path theory -> the cost is the LDS A-path (256KB/WG/step,
// 8 waves each reading the full 32KB h tile + 4.2M conflict cycles). This round
// removes LDS from the A-path entirely:
//   wave wv = (ks=wv>>1: K-quarter of 256, ng=wv&1: 16-unit col group).
//   A-frags: 8x global_load_dwordx4 sc0sc1 directly from hbuf (16 rows x 64B
//   contiguous per instr); each aQ[kt] reused across 4 col-frags (nf).
//   B: 128 AGPRs/lane (r14 mechanism), quad q = nf*8+kt.
//   K-partials combined via zxP[frag][ln][slot^ln] (f32x4; XOR keeps banks
//   uniform); gate wave wv owns frag wv -> gate/publish/sync code unchanged.
__global__ __attribute__((amdgpu_flat_work_group_size(512, 512), amdgpu_waves_per_eu(2, 2)))
void lstm_kernel(const float* __restrict__ xg,      // [2048][4096] f32
                 const u16* __restrict__ Wht,       // [4096][1024] bf16 (n-major)
                 const u64* __restrict__ maskb,     // [16][2] bitmask
                 const float* __restrict__ ench, const float* __restrict__ encc,
                 const float* __restrict__ gamma, const float* __restrict__ beta,
                 const float* __restrict__ mmean, const float* __restrict__ mvar,
                 u32* __restrict__ hbuf32,          // [2][16][512] u32 (linear)
                 u16* __restrict__ hbn,             // [2048][1024] bf16 out
                 u32* __restrict__ cnt) {
  __shared__ f32x4 zxP[8][16][16];     // 32KB k-partial exchange

  const int wg = blockIdx.x;           // 0..31
  const int u0 = wg << 5;              // 32 units per WG
  const int tid = threadIdx.x;
  const int lane = tid & 63;
  const int wv = tid >> 6;             // 0..7
  const int ln = lane & 15, khq = lane >> 4;
  const int ks = wv >> 1, ng = wv & 1; // compute role: K-quarter, col group

  const int g = ln & 3;                // gate index (i,f,cc,o)
  const int unit = u0 + wv * 4 + (ln >> 2);   // gate-role unit (frag wv)

  // ---- Wh preload into 128 AGPRs/lane: quad q=nf*8+kt, cols of frag ng*4+nf,
  //      K window ks*256 + kt*32 ----
  u32 bA[128];
  {
#pragma unroll
    for (int gq = 0; gq < 4; ++gq) {
      u32x4 t[8];
#pragma unroll
      for (int j = 0; j < 8; ++j) {
        int qi = gq * 8 + j;
        int nf = qi >> 3, kt = qi & 7;
        const u16* pp = Wht + (size_t)(g * 1024 + u0 + ng * 16 + nf * 4 + (ln >> 2)) * 1024
                        + ks * 256 + kt * 32 + khq * 8;
        asm volatile("global_load_dwordx4 %0, %1, off" : "=v"(t[j]) : "v"(pp));
      }
      asm volatile("s_waitcnt vmcnt(0)" ::: "memory");
      __builtin_amdgcn_sched_barrier(0);
#pragma unroll
      for (int j = 0; j < 8; ++j) {
        int base = (gq * 8 + j) * 4;
        asm volatile("v_accvgpr_write_b32 %0, %1" : "=a"(bA[base + 0]) : "v"(t[j].x));
        asm volatile("v_accvgpr_write_b32 %0, %1" : "=a"(bA[base + 1]) : "v"(t[j].y));
        asm volatile("v_accvgpr_write_b32 %0, %1" : "=a"(bA[base + 2]) : "v"(t[j].z));
        asm volatile("v_accvgpr_write_b32 %0, %1" : "=a"(bA[base + 3]) : "v"(t[j].w));
      }
    }
  }

  // per-lane gate-role state (frag wv)
  float cellR[4], holdR[4], xgr[4];
  u64 mA[4], mB[4];
  const float bn_s = gamma[unit] * rsqrtf(mvar[unit] + 1e-3f);
  const float bn_b = beta[unit] - mmean[unit] * bn_s;
  const size_t bstride = (size_t)128 * 4096;
  const float* xbase = xg + (size_t)(khq * 4) * bstride + g * 1024 + unit;
#pragma unroll
  for (int r = 0; r < 4; ++r) {
    int batch = khq * 4 + r;
    cellR[r] = encc[batch * 1024 + unit];
    holdR[r] = ench[batch * 1024 + unit];
    mA[r] = maskb[batch * 2];
    mB[r] = maskb[batch * 2 + 1];
  }
  // initial publish of h(0) into parity-0 buffer
#pragma unroll
  for (int r = 0; r < 4; ++r) {
    u32 w = (u32)f2bf(holdR[r]);
    u32 pw = (u32)__shfl_xor((int)w, 4);   // partner unit+1, same gate
    if ((ln & 7) == 0) {
      int batch = khq * 4 + r;
      AT_ST((u32*)((char*)hbuf32 + batch * 2048 + unit * 2), (w & 0xFFFFu) | (pw << 16));
    }
  }
#pragma unroll
  for (int r = 0; r < 4; ++r) xgr[r] = xbase[r * bstride];   // xg(0) prefetch
  asm volatile("s_waitcnt vmcnt(0)" ::: "memory");
  __syncthreads();
  if (tid == 0) {
    u32 oldv = AT_FAA(cnt);
    if (oldv != 31u) {
      int c = 0;
      while (AT_LD((const u32*)cnt) < 32u) {
        __builtin_amdgcn_s_sleep(1);
        if (++c > (1 << 18)) break;
      }
    }
  }
  __syncthreads();

  for (int s = 0; s < 128; ++s) {
    // ---- A-frags direct from hbuf: 8 x dwordx4 sc0sc1 (rows=batch ln,
    //      64B contiguous per row per instr), one waitcnt ----
    u32x4 aQ[8];
    {
      const char* abase = (const char*)hbuf32 + (s & 1) * 32768 +
                          ln * 2048 + ks * 512 + khq * 16;
#pragma unroll
      for (int kt = 0; kt < 8; ++kt) {
        const char* pp = abase + kt * 64;
        asm volatile("global_load_dwordx4 %0, %1, off sc0 sc1" : "=v"(aQ[kt]) : "v"(pp));
      }
      asm volatile("s_waitcnt vmcnt(0)" ::: "memory");
      __builtin_amdgcn_sched_barrier(0);
    }

    // ---- 32 MFMA: 4 independent acc chains (col-frags), aQ reused 4x ----
    f32x4 acc[4] = {};
#pragma unroll
    for (int kt = 0; kt < 8; ++kt) {
      s16x8 a = __builtin_bit_cast(s16x8, aQ[kt]);
#pragma unroll
      for (int nf = 0; nf < 4; ++nf) {
        int qi = (nf * 8 + kt) * 4;
        u32 w0, w1, w2, w3;
        asm("v_accvgpr_read_b32 %0, %1" : "=v"(w0) : "a"(bA[qi + 0]));
        asm("v_accvgpr_read_b32 %0, %1" : "=v"(w1) : "a"(bA[qi + 1]));
        asm("v_accvgpr_read_b32 %0, %1" : "=v"(w2) : "a"(bA[qi + 2]));
        asm("v_accvgpr_read_b32 %0, %1" : "=v"(w3) : "a"(bA[qi + 3]));
        u32x4 qv = {w0, w1, w2, w3};
        acc[nf] = __builtin_amdgcn_mfma_f32_16x16x32_bf16(
            a, __builtin_bit_cast(s16x8, qv), acc[nf], 0, 0, 0);
      }
    }

    // ---- k-partial exchange: slot XOR keeps bank load uniform ----
#pragma unroll
    for (int nf = 0; nf < 4; ++nf)
      zxP[ng * 4 + nf][ln][(ks * 4 + khq) ^ ln] = acc[nf];
    __syncthreads();                           // (A) partials ready

    // ---- gates (wave wv owns frag wv) + publish ----
    f32x4 zv = {0.f, 0.f, 0.f, 0.f};
#pragma unroll
    for (int k2 = 0; k2 < 4; ++k2)
      zv += zxP[wv][ln][(k2 * 4 + khq) ^ ln];

    u32 bnpair[4];
    {
      u16 hbb[4], hbnb[4];
#pragma unroll
      for (int r = 0; r < 4; ++r) {
        float z = zv[r] + xgr[r];
        float sig = 1.f / (1.f + __expf(-z));
        float val = (g == 2) ? fmaxf(z, 0.f) : sig;
        float v1 = __shfl_xor(val, 1);
        float v2 = __shfl_xor(val, 2);
        float v3 = __shfl_xor(val, 3);
        float cnew = v1 * cellR[r] + val * v2;   // f*c + i*cc (g==0 view)
        float hnew = v3 * fmaxf(cnew, 0.f);
        u64 mm = (s < 64) ? mA[r] : mB[r];
        if (!((mm >> (s & 63)) & 1)) { cnew = cellR[r]; hnew = holdR[r]; }
        cellR[r] = cnew;
        holdR[r] = hnew;
        hbb[r] = f2bf(hnew);
        hbnb[r] = f2bf(hnew * bn_s + bn_b);
      }
#pragma unroll
      for (int r = 0; r < 4; ++r) {
        u32 w = (u32)hbb[r] | ((u32)hbnb[r] << 16);
        u32 pw = (u32)__shfl_xor((int)w, 4);
        u32 hpair = (w & 0xFFFFu) | ((pw & 0xFFFFu) << 16);
        bnpair[r] = (w >> 16) | (pw & 0xFFFF0000u);
        if (s < 127 && (ln & 7) == 0) {
          int batch = khq * 4 + r;
          AT_ST((u32*)((char*)hbuf32 + ((s + 1) & 1) * 32768 + batch * 2048 + unit * 2), hpair);
        }
      }
    }

    if (s < 127) {
      asm volatile("s_waitcnt vmcnt(0)" ::: "memory");   // drain h publishes
      __syncthreads();                         // (B) publishes complete + zxP reads done
      u32 oldv = 0xFFFFFFFFu;
      if (tid == 0) oldv = AT_FAA(cnt);
      // deferred hbn stores + xg(s+1) prefetch overlap the poll
      if ((ln & 7) == 0) {
#pragma unroll
        for (int r = 0; r < 4; ++r) {
          int batch = khq * 4 + r;
          *(u32*)((char*)hbn + (size_t)(batch * 128 + s) * 2048 + unit * 2) = bnpair[r];
        }
      }
      {
        const float* xb = xbase + (size_t)(s + 1) * 4096;
#pragma unroll
        for (int r = 0; r < 4; ++r) xgr[r] = xb[r * bstride];
      }
      if (tid == 0) {
        const u32 target = (u32)(s + 2) * 32u;
        if (oldv != target - 1u) {
          int c = 0;
          while (AT_LD((const u32*)cnt) < target) {
            __builtin_amdgcn_s_sleep(1);
            if (++c > (1 << 18)) break;
          }
        }
      }
      __syncthreads();                         // (C) release
    } else if ((ln & 7) == 0) {
      // s == 127: final hbn stores
#pragma unroll
      for (int r = 0; r < 4; ++r) {
        int batch = khq * 4 + r;
        *(u32*)((char*)hbn + (size_t)(batch * 128 + s) * 2048 + unit * 2) = bnpair[r];
      }
    }
  }
}

// ---------- softmax finish ----------

// f32 path (fallback): in-place scale of f32 exp
__global__ void scale_kernel(float* __restrict__ out, const float* __restrict__ rs) {
  const int total4 = 16384000;              // 65,536,000 / 4
  for (int i = blockIdx.x * 256 + threadIdx.x; i < total4; i += gridDim.x * 256) {
    float4* p = (float4*)out + i;
    float4 v = *p;
    int row = i / 8000;                     // 8000 float4 per row
    float sF = 1.0f / rs[row];
    v.x *= sF; v.y *= sF; v.z *= sF; v.w *= sF;
    *p = v;
  }
}

// bf16 path: read bf16 exp, write normalized f32
__global__ void scale_bf_kernel(float* __restrict__ out, const u16* __restrict__ e,
                                const float* __restrict__ rs) {
  const int total8 = 8192000;               // 65,536,000 / 8
  for (int i = blockIdx.x * 256 + threadIdx.x; i < total8; i += gridDim.x * 256) {
    s16x8 v = ((const s16x8*)e)[i];
    int row = i / 4000;                     // 4000 8-groups per row
    float sF = 1.0f / rs[row];
    float4 o0, o1;
    o0.x = bf2f((u16)v[0]) * sF; o0.y = bf2f((u16)v[1]) * sF;
    o0.z = bf2f((u16)v[2]) * sF; o0.w = bf2f((u16)v[3]) * sF;
    o1.x = bf2f((u16)v[4]) * sF; o1.y = bf2f((u16)v[5]) * sF;
    o1.z = bf2f((u16)v[6]) * sF; o1.w = bf2f((u16)v[7]) * sF;
    ((float4*)out)[2 * i] = o0;
    ((float4*)out)[2 * i + 1] = o1;
  }
}

// ---------- launch ----------

extern "C" void kernel_launch(void* const* d_in, const int* in_sizes, int n_in,
                              void* d_out, int out_size, void* d_ws, size_t ws_size,
                              hipStream_t stream) {
  (void)in_sizes; (void)n_in; (void)out_size;
  const int*   inputs = (const int*)d_in[0];
  const float* ench   = (const float*)d_in[1];
  const float* encc   = (const float*)d_in[2];
  const float* emb    = (const float*)d_in[3];
  const float* Wx     = (const float*)d_in[4];
  const float* Wh     = (const float*)d_in[5];
  const float* bb     = (const float*)d_in[6];
  const float* gamma  = (const float*)d_in[7];
  const float* beta   = (const float*)d_in[8];
  const float* mmean  = (const float*)d_in[9];
  const float* mvar   = (const float*)d_in[10];
  const float* W1     = (const float*)d_in[11];
  const float* b1     = (const float*)d_in[12];
  const float* W2     = (const float*)d_in[13];
  const float* b2     = (const float*)d_in[14];
  float* out = (float*)d_out;

  char* p = (char*)d_ws;
  u32*   cnt    = (u32*)(p + 0);            // word 0
  float* rowsum = (float*)(p + 1024);       // 2048 floats; memset covers [0,9216)
  u64*   maskb  = (u64*)(p + 10240);        // 256B, written by mask_kernel
  u32*   hbuf32 = (u32*)(p + 16384);        // 64KB (2 x 32KB parity tiles)
  size_t off = 81920;
  u16*   xbf  = (u16*)(p + off);     off += (size_t)2048 * 512 * 2;     // 2MB
  u16*   Wxt  = (u16*)(p + off);     off += (size_t)4096 * 512 * 2;     // 4MB
  u16*   Wht  = (u16*)(p + off);     off += (size_t)4096 * 1024 * 2;    // 8MB
  u16*   W1t  = (u16*)(p + off);     off += (size_t)1024 * 1024 * 2;    // 2MB
  u16*   W2t  = (u16*)(p + off);     off += (size_t)32000 * 1024 * 2;   // 64MB
  float* xg   = (float*)(p + off);   off += (size_t)2048 * 4096 * 4;    // 32MB
  u16*   hbn  = (u16*)(p + off);     off += (size_t)2048 * 1024 * 2;    // 4MB
  u16*   d1   = (u16*)(p + off);     off += (size_t)2048 * 1024 * 2;    // 4MB
  size_t off_base = off;
  u16*   expbf = (u16*)(p + off);    off += (size_t)2048 * 32000 * 2;   // 125MB (optional)
  if (ws_size < off_base) return;  // insufficient scratch; avoid OOB
  const bool bf16path = (ws_size >= off);

  hipMemsetAsync(d_ws, 0, 9216, stream);  // cnt + rowsum

  embed_kernel<<<512, 256, 0, stream>>>(inputs, emb, xbf);
  mask_kernel<<<1, 64, 0, stream>>>(inputs, maskb);
  transpose_bf16<<<(512 / 32) * (4096 / 32), 256, 0, stream>>>(Wx, Wxt, 512, 4096);
  transpose_bf16<<<(1024 / 32) * (4096 / 32), 256, 0, stream>>>(Wh, Wht, 1024, 4096);
  transpose_bf16<<<(1024 / 32) * (1024 / 32), 256, 0, stream>>>(W1, W1t, 1024, 1024);
  transpose_bf16<<<(1024 / 32) * (32000 / 32), 256, 0, stream>>>(W2, W2t, 1024, 32000);

  gemm_bf16<0><<<16 * 32, 256, 0, stream>>>(xbf, Wxt, bb, xg, nullptr, 2048, 4096, 512);

  lstm_kernel<<<32, 512, 0, stream>>>(xg, Wht, maskb, ench, encc, gamma, beta,
                                      mmean, mvar, hbuf32, hbn, cnt);

  gemm_bf16<1><<<16 * 8, 256, 0, stream>>>(hbn, W1t, b1, d1, nullptr, 2048, 1024, 1024);

  if (bf16path) {
    gemm256_exp<<<8 * 125, 512, 0, stream>>>(d1, W2t, b2, expbf, rowsum, 2048, 32000, 1024);
    scale_bf_kernel<<<2048, 256, 0, stream>>>(out, expbf, rowsum);
  } else {
    gemm_bf16<2><<<16 * 250, 256, 0, stream>>>(d1, W2t, b2, out, rowsum, 2048, 32000, 1024);
    scale_kernel<<<2048, 256, 0, stream>>>(out, rowsum);
  }
}

// Round 16
// 899.857 us; speedup vs baseline: 1.1241x; 1.1241x over previous
//
#include <hip/hip_runtime.h>
#include <hip/hip_bf16.h>
#include <stdint.h>

typedef unsigned short u16;
typedef unsigned int u32;
typedef unsigned long long u64;
typedef __attribute__((ext_vector_type(4))) float f32x4;
typedef __attribute__((ext_vector_type(8))) short s16x8;
typedef __attribute__((ext_vector_type(4))) unsigned int u32x4;

#define AT_LD(p)    __hip_atomic_load((p), __ATOMIC_RELAXED, __HIP_MEMORY_SCOPE_AGENT)
#define AT_ST(p, v) __hip_atomic_store((p), (v), __ATOMIC_RELAXED, __HIP_MEMORY_SCOPE_AGENT)
#define AT_FAA(p)   __hip_atomic_fetch_add((p), 1u, __ATOMIC_RELAXED, __HIP_MEMORY_SCOPE_AGENT)

// ---------- helpers ----------

static __device__ __forceinline__ u16 f2bf(float f) {
  union { float f; unsigned u; } v; v.f = f;
  unsigned r = v.u + 0x7FFFu + ((v.u >> 16) & 1u);
  return (u16)(r >> 16);
}

static __device__ __forceinline__ float bf2f(u16 b) {
  union { unsigned u; float f; } v; v.u = ((u32)b) << 16;
  return v.f;
}

static __device__ __forceinline__ void gload_lds16(const void* g, void* l) {
  __builtin_amdgcn_global_load_lds(
      (const __attribute__((address_space(1))) unsigned int*)(uintptr_t)g,
      (__attribute__((address_space(3))) unsigned int*)(uintptr_t)l,
      16, 0, 0);
}

// bank-balancing swizzle for the 32KB h tile in LDS (r6/r7 proven).
static __device__ __forceinline__ int swzB(int B) {
  int pos = (B >> 4) & 127;
  int row = (B >> 11) & 15;
  int slot = (pos ^ row ^ (pos >> 3)) & 7;
  int npos = (pos & 0x78) | slot;
  return (B & ~0x7F0) | (npos << 4);
}

// ---------- pre-pass kernels ----------

__global__ void embed_kernel(const int* __restrict__ inputs,
                             const float* __restrict__ emb,
                             u16* __restrict__ xbf) {
  int i = blockIdx.x * 256 + threadIdx.x;   // 131072 threads
  int row = i >> 6;
  int e0 = (i & 63) << 3;
  int tok = inputs[row];
  const float* src = emb + (size_t)tok * 512 + e0;
  s16x8 o;
#pragma unroll
  for (int j = 0; j < 8; ++j) o[j] = (short)f2bf(src[j]);
  *(s16x8*)(xbf + (size_t)row * 512 + e0) = o;
}

// bit-pack mask: maskb[b*2+h] bit j = (inputs[b*128 + h*64 + j] != 0)
__global__ void mask_kernel(const int* __restrict__ inputs, u64* __restrict__ mb) {
  int t = threadIdx.x;
  if (t < 32) {
    int b = t >> 1, h = t & 1;
    u64 m = 0;
    for (int j = 0; j < 64; ++j)
      m |= (u64)(inputs[b * 128 + h * 64 + j] != 0) << j;
    mb[t] = m;
  }
}

// Wt[n][k] = bf16(W[k][n]); K,N multiples of 32
__global__ void transpose_bf16(const float* __restrict__ W, u16* __restrict__ Wt,
                               int K, int N) {
  __shared__ float t[32][33];
  int ntn = N >> 5;
  int tn = blockIdx.x % ntn, tk = blockIdx.x / ntn;
  int n0 = tn << 5, k0 = tk << 5;
  int tx = threadIdx.x & 31, ty = threadIdx.x >> 5;  // ty 0..7
#pragma unroll
  for (int j = 0; j < 4; ++j) {
    int k = ty * 4 + j;
    t[k][tx] = W[(size_t)(k0 + k) * N + n0 + tx];
  }
  __syncthreads();
#pragma unroll
  for (int j = 0; j < 4; ++j) {
    int n = ty * 4 + j;
    Wt[(size_t)(n0 + n) * K + k0 + tx] = f2bf(t[tx][n]);
  }
}

// ---------- m97-style bf16 GEMM, 128x128 tile, BK=32 ----------
// MODE 0: C=f32, store acc+bias          (xg)
// MODE 1: C=bf16, store relu(acc+bias)   (d1)
// MODE 2: C=f32, store exp(acc+bias), atomicAdd row sums (fallback path)
template <int MODE>
__global__ __launch_bounds__(256)
void gemm_bf16(const u16* __restrict__ A, const u16* __restrict__ Bt,
               const float* __restrict__ bias, void* __restrict__ Cptr,
               float* __restrict__ rowsum, int M, int N, int K) {
  (void)M;
  __shared__ u16 sA[128 * 32];
  __shared__ u16 sB[128 * 32];
  const int nbn = N >> 7;
  const int nwg = gridDim.x;
  int bid = blockIdx.x;
  int q = nwg >> 3;                         // grids are multiples of 8
  int swz = (bid & 7) * q + (bid >> 3);     // XCD-aware swizzle (bijective)
  int bm = swz / nbn, bn = swz % nbn;
  const int brow = bm << 7, bcol = bn << 7;

  const int tid = threadIdx.x;
  const int lane = tid & 63;
  const int wv = tid >> 6;
  const int wr = (wv >> 1) * 64, wc = (wv & 1) * 64;
  const int ln = lane & 15, kh = lane >> 4;

  const int srow = tid >> 2;                // 0..63
  const int kch = (tid & 3) << 3;           // 0,8,16,24 (elements)

  f32x4 acc[4][4] = {};

  const int nk = K >> 5;
  const u16* Abase = A + (size_t)(brow + srow) * K + kch;
  const u16* Bbase = Bt + (size_t)(bcol + srow) * K + kch;
  const size_t rstride = (size_t)64 * K;
  u16* lA = sA + srow * 32 + kch;
  u16* lB = sB + srow * 32 + kch;

  for (int kt = 0; kt < nk; ++kt) {
    const int k0 = kt << 5;
    gload_lds16(Abase + k0, lA);
    gload_lds16(Abase + rstride + k0, lA + 64 * 32);
    gload_lds16(Bbase + k0, lB);
    gload_lds16(Bbase + rstride + k0, lB + 64 * 32);
    __syncthreads();
    s16x8 aF[4], bF[4];
#pragma unroll
    for (int m = 0; m < 4; ++m)
      aF[m] = *(const s16x8*)(sA + (wr + m * 16 + ln) * 32 + kh * 8);
#pragma unroll
    for (int n = 0; n < 4; ++n)
      bF[n] = *(const s16x8*)(sB + (wc + n * 16 + ln) * 32 + kh * 8);
#pragma unroll
    for (int m = 0; m < 4; ++m)
#pragma unroll
      for (int n = 0; n < 4; ++n)
        acc[m][n] = __builtin_amdgcn_mfma_f32_16x16x32_bf16(aF[m], bF[n], acc[m][n], 0, 0, 0);
    __syncthreads();
  }

  const int browq = brow + wr;
  const int bcolq = bcol + wc;

  if (MODE == 1) {
    u16* O = (u16*)Cptr;
#pragma unroll
    for (int n = 0; n < 4; ++n) {
      int gcol = bcolq + n * 16 + ln;
      float bv = bias[gcol];
#pragma unroll
      for (int m = 0; m < 4; ++m)
#pragma unroll
        for (int r = 0; r < 4; ++r) {
          int grow = browq + m * 16 + kh * 4 + r;
          float v = fmaxf(acc[m][n][r] + bv, 0.f);
          O[(size_t)grow * N + gcol] = f2bf(v);
        }
    }
  } else {
    float* O = (float*)Cptr;
    float rs[4][4] = {};
#pragma unroll
    for (int n = 0; n < 4; ++n) {
      int gcol = bcolq + n * 16 + ln;
      float bv = bias[gcol];
#pragma unroll
      for (int m = 0; m < 4; ++m)
#pragma unroll
        for (int r = 0; r < 4; ++r) {
          int grow = browq + m * 16 + kh * 4 + r;
          float v = acc[m][n][r] + bv;
          if (MODE == 2) { v = __expf(v); rs[m][r] += v; }
          O[(size_t)grow * N + gcol] = v;
        }
    }
    if (MODE == 2) {
#pragma unroll
      for (int m = 0; m < 4; ++m)
#pragma unroll
        for (int r = 0; r < 4; ++r) {
          float v = rs[m][r];
          v += __shfl_xor(v, 1);
          v += __shfl_xor(v, 2);
          v += __shfl_xor(v, 4);
          v += __shfl_xor(v, 8);
          if (ln == 0) atomicAdd(&rowsum[browq + m * 16 + kh * 4 + r], v);
        }
    }
  }
}

// ---------- 256x256-tile logits GEMM, counted-vmcnt 4-buffer pipeline ----------
// DEPTH-3 prefetch (r16): 1 WG/CU (128KB LDS; 190 VGPR forbids 2 WGs), so
// exposed staging latency has no TLP cover -> hide it with a third in-flight
// tile. Prologue stages 0..2; loop stages t+3; wait vmcnt(8) keeps tiles
// t+2,t+3 flying; tail 8->4->0.
__global__ __launch_bounds__(512, 1)
void gemm256_exp(const u16* __restrict__ A, const u16* __restrict__ Bt,
                 const float* __restrict__ bias, u16* __restrict__ O,
                 float* __restrict__ rowsum, int M, int N, int K) {
  (void)M;
  __shared__ char lds[131072];              // 4 bufs x 32KB
  const int nbn = N >> 8;                   // 125
  const int nwg = gridDim.x;                // 1000 (multiple of 8)
  int bid = blockIdx.x;
  int q = nwg >> 3;
  int swz = (bid & 7) * q + (bid >> 3);     // XCD swizzle (bijective)
  int bm = swz / nbn, bn = swz % nbn;
  const int brow = bm << 8, bcol = bn << 8;

  const int tid = threadIdx.x;
  const int lane = tid & 63;
  const int wv = tid >> 6;                  // 0..7
  const int wm = wv >> 2, wn = wv & 3;
  const int ln = lane & 15, kh = lane >> 4;

  const int nk = K >> 5;                    // 32

  const u16* sbase[4];
#pragma unroll
  for (int j = 0; j < 4; ++j) {
    int cc = (j & 1) * 512 + wv * 64 + lane;
    int row = cc >> 2, pcol = cc & 3;
    int lcol = pcol ^ ((row >> 1) & 3);
    sbase[j] = (j < 2 ? A + (size_t)(brow + row) * K
                      : Bt + (size_t)(bcol + row) * K) + lcol * 8;
  }

#define STAGE256(kt, buf)                                                  \
  {                                                                        \
    char* lb = lds + (buf) * 32768 + wv * 1024;                            \
    _Pragma("unroll")                                                      \
    for (int j = 0; j < 4; ++j)                                            \
      gload_lds16(sbase[j] + (kt) * 32, lb + j * 8192);                    \
  }

  f32x4 acc[8][4] = {};

  STAGE256(0, 0);
  STAGE256(1, 1);
  STAGE256(2, 2);
  asm volatile("s_waitcnt vmcnt(8)" ::: "memory");   // tile 0 landed (1,2 flying)
  __syncthreads();

  const char* Ab = lds + (size_t)(wm * 128) * 64;
  const char* Bb = lds + 16384 + (size_t)(wn * 64) * 64;
  const int cswz = (kh ^ ((ln >> 1) & 3)) * 16 + ln * 64;

  for (int t = 0; t < nk; ++t) {
    const int boff = (t & 3) * 32768;
    if (t + 3 < nk) STAGE256(t + 3, (t + 3) & 3);
    s16x8 aF[8], bF[4];
#pragma unroll
    for (int m = 0; m < 8; ++m)
      aF[m] = *(const s16x8*)(Ab + boff + m * 1024 + cswz);
#pragma unroll
    for (int n = 0; n < 4; ++n)
      bF[n] = *(const s16x8*)(Bb + boff + n * 1024 + cswz);
    __builtin_amdgcn_s_setprio(1);
#pragma unroll
    for (int m = 0; m < 8; ++m)
#pragma unroll
      for (int n = 0; n < 4; ++n)
        acc[m][n] = __builtin_amdgcn_mfma_f32_16x16x32_bf16(aF[m], bF[n], acc[m][n], 0, 0, 0);
    __builtin_amdgcn_s_setprio(0);
    if (t + 3 < nk)
      asm volatile("s_waitcnt vmcnt(8)" ::: "memory");   // t+1 landed; t+2,t+3 fly
    else if (t + 2 < nk)
      asm volatile("s_waitcnt vmcnt(4)" ::: "memory");   // t+1 landed; t+2 flies
    else if (t + 1 < nk)
      asm volatile("s_waitcnt vmcnt(0)" ::: "memory");   // drain last tile
    if (t < nk - 1) __syncthreads();
  }

  // ---- fused softmax-exp epilogue ----
  const int browq = brow + wm * 128;
  const int bcolq = bcol + wn * 64;
  float rs[8][4] = {};
#pragma unroll
  for (int n = 0; n < 4; ++n) {
    int gcol = bcolq + n * 16 + ln;
    float bv = bias[gcol];
#pragma unroll
    for (int m = 0; m < 8; ++m)
#pragma unroll
      for (int r = 0; r < 4; ++r) {
        float v = __expf(acc[m][n][r] + bv);
        rs[m][r] += v;
        O[(size_t)(browq + m * 16 + kh * 4 + r) * N + gcol] = f2bf(v);
      }
  }
#pragma unroll
  for (int m = 0; m < 8; ++m)
#pragma unroll
    for (int r = 0; r < 4; ++r) {
      float v = rs[m][r];
      v += __shfl_xor(v, 1);
      v += __shfl_xor(v, 2);
      v += __shfl_xor(v, 4);
      v += __shfl_xor(v, 8);
      if (ln == 0) atomicAdd(&rowsum[browq + m * 16 + kh * 4 + r], v);
    }
#undef STAGE256
}

// ---------- persistent LSTM: 32 WGs x 512 threads, full-K waves ----------
// Reverted to the best measured config (r11/r12, 484us). Post-r15 ledger:
// sync mechanism (r2-r4, r8-r10), B-residency (r13-r14), and LDS-A-path (r15)
// all falsified as dominant costs; per-step time = serialized fabric RTs
// (publish-drain, FAA, observe, stage) + compute, at this structure's floor.
__global__ __launch_bounds__(512, 1)
void lstm_kernel(const float* __restrict__ xg,      // [2048][4096] f32
                 const u16* __restrict__ Wht,       // [4096][1024] bf16 (n-major)
                 const u64* __restrict__ maskb,     // [16][2] bitmask
                 const float* __restrict__ ench, const float* __restrict__ encc,
                 const float* __restrict__ gamma, const float* __restrict__ beta,
                 const float* __restrict__ mmean, const float* __restrict__ mvar,
                 u32* __restrict__ hbuf32,          // [2][16][512] u32 (linear)
                 u16* __restrict__ hbn,             // [2048][1024] bf16 out
                 u32* __restrict__ cnt) {
  __shared__ char hA[32 * 1024];       // staged h(s), swzB-swizzled

  const int wg = blockIdx.x;           // 0..31
  const int u0 = wg << 5;              // 32 units per WG
  const int tid = threadIdx.x;
  const int lane = tid & 63;
  const int wv = tid >> 6;             // 0..7
  const int ln = lane & 15, khq = lane >> 4;

  const int g = ln & 3;                // gate index (i,f,cc,o)
  const int unit = u0 + wv * 4 + (ln >> 2);

  // ---- Wh preload: 32 x 16B via inline asm ----
  u32x4 bWq[32];
  {
    const u16* wrow = Wht + (size_t)(g * 1024 + unit) * 1024 + khq * 8;
#pragma unroll
    for (int kt = 0; kt < 32; ++kt) {
      const u16* pp = wrow + kt * 32;
      asm volatile("global_load_dwordx4 %0, %1, off" : "=v"(bWq[kt]) : "v"(pp));
    }
    asm volatile("s_waitcnt vmcnt(0)" ::: "memory");
  }

  // per-lane state (g==0 lanes meaningful after shfl combine)
  float cellR[4], holdR[4], xgr[4];
  u64 mA[4], mB[4];
  const float bn_s = gamma[unit] * rsqrtf(mvar[unit] + 1e-3f);
  const float bn_b = beta[unit] - mmean[unit] * bn_s;
  const size_t bstride = (size_t)128 * 4096;
  const float* xbase = xg + (size_t)(khq * 4) * bstride + g * 1024 + unit;
#pragma unroll
  for (int r = 0; r < 4; ++r) {
    int batch = khq * 4 + r;
    cellR[r] = encc[batch * 1024 + unit];
    holdR[r] = ench[batch * 1024 + unit];
    mA[r] = maskb[batch * 2];
    mB[r] = maskb[batch * 2 + 1];
  }
  // initial publish of h(0) into parity-0 buffer
#pragma unroll
  for (int r = 0; r < 4; ++r) {
    u32 w = (u32)f2bf(holdR[r]);
    u32 pw = (u32)__shfl_xor((int)w, 4);   // partner unit+1, same gate
    if ((ln & 7) == 0) {
      int batch = khq * 4 + r;
      AT_ST((u32*)((char*)hbuf32 + batch * 2048 + unit * 2), (w & 0xFFFFu) | (pw << 16));
    }
  }
#pragma unroll
  for (int r = 0; r < 4; ++r) xgr[r] = xbase[r * bstride];   // xg(0) prefetch
  asm volatile("s_waitcnt vmcnt(0)" ::: "memory");
  __syncthreads();
  if (tid == 0) {
    u32 oldv = AT_FAA(cnt);
    if (oldv != 31u) {
      int c = 0;
      while (AT_LD((const u32*)cnt) < 32u) {
        __builtin_amdgcn_s_sleep(1);
        if (++c > (1 << 18)) break;
      }
    }
  }
  __syncthreads();

  for (int s = 0; s < 128; ++s) {
    // ---- stage h(s): 8 back-to-back uncached u64 loads, one waitcnt ----
    u64 st[8];
    {
      const u64* base = (const u64*)((const char*)hbuf32 + (s & 1) * 32768) + tid;
#pragma unroll
      for (int k = 0; k < 8; ++k) {
        const u64* pp = base + k * 512;
        asm volatile("global_load_dwordx2 %0, %1, off sc0 sc1" : "=v"(st[k]) : "v"(pp));
      }
      asm volatile("s_waitcnt vmcnt(0)" ::: "memory");
      __builtin_amdgcn_sched_barrier(0);
#pragma unroll
      for (int k = 0; k < 8; ++k)
        *(u64*)(hA + swzB((tid + k * 512) * 8)) = st[k];
    }
    __syncthreads();                           // (A) hA ready

    // ---- 32 MFMA over full K, 2 chains; A from LDS ----
    f32x4 acc0 = {0.f, 0.f, 0.f, 0.f};
    f32x4 acc1 = {0.f, 0.f, 0.f, 0.f};
#pragma unroll
    for (int kt = 0; kt < 32; kt += 2) {
      s16x8 a0 = *(const s16x8*)(hA + swzB(ln * 2048 + kt * 64 + khq * 16));
      acc0 = __builtin_amdgcn_mfma_f32_16x16x32_bf16(
          a0, __builtin_bit_cast(s16x8, bWq[kt]), acc0, 0, 0, 0);
      s16x8 a1 = *(const s16x8*)(hA + swzB(ln * 2048 + (kt + 1) * 64 + khq * 16));
      acc1 = __builtin_amdgcn_mfma_f32_16x16x32_bf16(
          a1, __builtin_bit_cast(s16x8, bWq[kt + 1]), acc1, 0, 0, 0);
    }
    f32x4 accs = acc0 + acc1;

    // ---- gates fully in-wave (lane quads hold i,f,cc,o) + publish ----
    u32 bnpair[4];
    {
      u16 hbb[4], hbnb[4];
#pragma unroll
      for (int r = 0; r < 4; ++r) {
        float z = accs[r] + xgr[r];
        float sig = 1.f / (1.f + __expf(-z));
        float val = (g == 2) ? fmaxf(z, 0.f) : sig;
        float v1 = __shfl_xor(val, 1);
        float v2 = __shfl_xor(val, 2);
        float v3 = __shfl_xor(val, 3);
        float cnew = v1 * cellR[r] + val * v2;   // f*c + i*cc (g==0 view)
        float hnew = v3 * fmaxf(cnew, 0.f);
        u64 mm = (s < 64) ? mA[r] : mB[r];
        if (!((mm >> (s & 63)) & 1)) { cnew = cellR[r]; hnew = holdR[r]; }
        cellR[r] = cnew;
        holdR[r] = hnew;
        hbb[r] = f2bf(hnew);
        hbnb[r] = f2bf(hnew * bn_s + bn_b);
      }
#pragma unroll
      for (int r = 0; r < 4; ++r) {
        u32 w = (u32)hbb[r] | ((u32)hbnb[r] << 16);
        u32 pw = (u32)__shfl_xor((int)w, 4);
        u32 hpair = (w & 0xFFFFu) | ((pw & 0xFFFFu) << 16);
        bnpair[r] = (w >> 16) | (pw & 0xFFFF0000u);
        if (s < 127 && (ln & 7) == 0) {
          int batch = khq * 4 + r;
          AT_ST((u32*)((char*)hbuf32 + ((s + 1) & 1) * 32768 + batch * 2048 + unit * 2), hpair);
        }
      }
    }

    if (s < 127) {
      asm volatile("s_waitcnt vmcnt(0)" ::: "memory");   // drain h publishes
      __syncthreads();                         // (B) all publishes complete
      u32 oldv = 0xFFFFFFFFu;
      if (tid == 0) oldv = AT_FAA(cnt);
      // deferred hbn stores + xg(s+1) prefetch overlap the poll
      if ((ln & 7) == 0) {
#pragma unroll
        for (int r = 0; r < 4; ++r) {
          int batch = khq * 4 + r;
          *(u32*)((char*)hbn + (size_t)(batch * 128 + s) * 2048 + unit * 2) = bnpair[r];
        }
      }
      {
        const float* xb = xbase + (size_t)(s + 1) * 4096;
#pragma unroll
        for (int r = 0; r < 4; ++r) xgr[r] = xb[r * bstride];
      }
      if (tid == 0) {
        const u32 target = (u32)(s + 2) * 32u;
        if (oldv != target - 1u) {
          int c = 0;
          while (AT_LD((const u32*)cnt) < target) {
            __builtin_amdgcn_s_sleep(1);
            if (++c > (1 << 18)) break;
          }
        }
      }
      __syncthreads();                         // (C) release
    } else if ((ln & 7) == 0) {
      // s == 127: final hbn stores
#pragma unroll
      for (int r = 0; r < 4; ++r) {
        int batch = khq * 4 + r;
        *(u32*)((char*)hbn + (size_t)(batch * 128 + s) * 2048 + unit * 2) = bnpair[r];
      }
    }
  }
}

// ---------- softmax finish ----------

// f32 path (fallback): in-place scale of f32 exp
__global__ void scale_kernel(float* __restrict__ out, const float* __restrict__ rs) {
  const int total4 = 16384000;              // 65,536,000 / 4
  for (int i = blockIdx.x * 256 + threadIdx.x; i < total4; i += gridDim.x * 256) {
    float4* p = (float4*)out + i;
    float4 v = *p;
    int row = i / 8000;                     // 8000 float4 per row
    float sF = 1.0f / rs[row];
    v.x *= sF; v.y *= sF; v.z *= sF; v.w *= sF;
    *p = v;
  }
}

// bf16 path: read bf16 exp, write normalized f32
__global__ void scale_bf_kernel(float* __restrict__ out, const u16* __restrict__ e,
                                const float* __restrict__ rs) {
  const int total8 = 8192000;               // 65,536,000 / 8
  for (int i = blockIdx.x * 256 + threadIdx.x; i < total8; i += gridDim.x * 256) {
    s16x8 v = ((const s16x8*)e)[i];
    int row = i / 4000;                     // 4000 8-groups per row
    float sF = 1.0f / rs[row];
    float4 o0, o1;
    o0.x = bf2f((u16)v[0]) * sF; o0.y = bf2f((u16)v[1]) * sF;
    o0.z = bf2f((u16)v[2]) * sF; o0.w = bf2f((u16)v[3]) * sF;
    o1.x = bf2f((u16)v[4]) * sF; o1.y = bf2f((u16)v[5]) * sF;
    o1.z = bf2f((u16)v[6]) * sF; o1.w = bf2f((u16)v[7]) * sF;
    ((float4*)out)[2 * i] = o0;
    ((float4*)out)[2 * i + 1] = o1;
  }
}

// ---------- launch ----------

extern "C" void kernel_launch(void* const* d_in, const int* in_sizes, int n_in,
                              void* d_out, int out_size, void* d_ws, size_t ws_size,
                              hipStream_t stream) {
  (void)in_sizes; (void)n_in; (void)out_size;
  const int*   inputs = (const int*)d_in[0];
  const float* ench   = (const float*)d_in[1];
  const float* encc   = (const float*)d_in[2];
  const float* emb    = (const float*)d_in[3];
  const float* Wx     = (const float*)d_in[4];
  const float* Wh     = (const float*)d_in[5];
  const float* bb     = (const float*)d_in[6];
  const float* gamma  = (const float*)d_in[7];
  const float* beta   = (const float*)d_in[8];
  const float* mmean  = (const float*)d_in[9];
  const float* mvar   = (const float*)d_in[10];
  const float* W1     = (const float*)d_in[11];
  const float* b1     = (const float*)d_in[12];
  const float* W2     = (const float*)d_in[13];
  const float* b2     = (const float*)d_in[14];
  float* out = (float*)d_out;

  char* p = (char*)d_ws;
  u32*   cnt    = (u32*)(p + 0);            // word 0
  float* rowsum = (float*)(p + 1024);       // 2048 floats; memset covers [0,9216)
  u64*   maskb  = (u64*)(p + 10240);        // 256B, written by mask_kernel
  u32*   hbuf32 = (u32*)(p + 16384);        // 64KB (2 x 32KB parity tiles)
  size_t off = 81920;
  u16*   xbf  = (u16*)(p + off);     off += (size_t)2048 * 512 * 2;     // 2MB
  u16*   Wxt  = (u16*)(p + off);     off += (size_t)4096 * 512 * 2;     // 4MB
  u16*   Wht  = (u16*)(p + off);     off += (size_t)4096 * 1024 * 2;    // 8MB
  u16*   W1t  = (u16*)(p + off);     off += (size_t)1024 * 1024 * 2;    // 2MB
  u16*   W2t  = (u16*)(p + off);     off += (size_t)32000 * 1024 * 2;   // 64MB
  float* xg   = (float*)(p + off);   off += (size_t)2048 * 4096 * 4;    // 32MB
  u16*   hbn  = (u16*)(p + off);     off += (size_t)2048 * 1024 * 2;    // 4MB
  u16*   d1   = (u16*)(p + off);     off += (size_t)2048 * 1024 * 2;    // 4MB
  size_t off_base = off;
  u16*   expbf = (u16*)(p + off);    off += (size_t)2048 * 32000 * 2;   // 125MB (optional)
  if (ws_size < off_base) return;  // insufficient scratch; avoid OOB
  const bool bf16path = (ws_size >= off);

  hipMemsetAsync(d_ws, 0, 9216, stream);  // cnt + rowsum

  embed_kernel<<<512, 256, 0, stream>>>(inputs, emb, xbf);
  mask_kernel<<<1, 64, 0, stream>>>(inputs, maskb);
  transpose_bf16<<<(512 / 32) * (4096 / 32), 256, 0, stream>>>(Wx, Wxt, 512, 4096);
  transpose_bf16<<<(1024 / 32) * (4096 / 32), 256, 0, stream>>>(Wh, Wht, 1024, 4096);
  transpose_bf16<<<(1024 / 32) * (1024 / 32), 256, 0, stream>>>(W1, W1t, 1024, 1024);
  transpose_bf16<<<(1024 / 32) * (32000 / 32), 256, 0, stream>>>(W2, W2t, 1024, 32000);

  gemm_bf16<0><<<16 * 32, 256, 0, stream>>>(xbf, Wxt, bb, xg, nullptr, 2048, 4096, 512);

  lstm_kernel<<<32, 512, 0, stream>>>(xg, Wht, maskb, ench, encc, gamma, beta,
                                      mmean, mvar, hbuf32, hbn, cnt);

  gemm_bf16<1><<<16 * 8, 256, 0, stream>>>(hbn, W1t, b1, d1, nullptr, 2048, 1024, 1024);

  if (bf16path) {
    gemm256_exp<<<8 * 125, 512, 0, stream>>>(d1, W2t, b2, expbf, rowsum, 2048, 32000, 1024);
    scale_bf_kernel<<<2048, 256, 0, stream>>>(out, expbf, rowsum);
  } else {
    gemm_bf16<2><<<16 * 250, 256, 0, stream>>>(d1, W2t, b2, out, rowsum, 2048, 32000, 1024);
    scale_kernel<<<2048, 256, 0, stream>>>(out, rowsum);
  }
}

// Round 17
// 887.057 us; speedup vs baseline: 1.1404x; 1.0144x over previous
//
#include <hip/hip_runtime.h>
#include <hip/hip_bf16.h>
#include <stdint.h>

typedef unsigned short u16;
typedef unsigned int u32;
typedef unsigned long long u64;
typedef __attribute__((ext_vector_type(4))) float f32x4;
typedef __attribute__((ext_vector_type(8))) short s16x8;
typedef __attribute__((ext_vector_type(4))) unsigned int u32x4;

#define AT_LD(p)    __hip_atomic_load((p), __ATOMIC_RELAXED, __HIP_MEMORY_SCOPE_AGENT)
#define AT_ST(p, v) __hip_atomic_store((p), (v), __ATOMIC_RELAXED, __HIP_MEMORY_SCOPE_AGENT)
#define AT_FAA(p)   __hip_atomic_fetch_add((p), 1u, __ATOMIC_RELAXED, __HIP_MEMORY_SCOPE_AGENT)

// ---------- helpers ----------

static __device__ __forceinline__ u16 f2bf(float f) {
  union { float f; unsigned u; } v; v.f = f;
  unsigned r = v.u + 0x7FFFu + ((v.u >> 16) & 1u);
  return (u16)(r >> 16);
}

static __device__ __forceinline__ float bf2f(u16 b) {
  union { unsigned u; float f; } v; v.u = ((u32)b) << 16;
  return v.f;
}

static __device__ __forceinline__ void gload_lds16(const void* g, void* l) {
  __builtin_amdgcn_global_load_lds(
      (const __attribute__((address_space(1))) unsigned int*)(uintptr_t)g,
      (__attribute__((address_space(3))) unsigned int*)(uintptr_t)l,
      16, 0, 0);
}

// bank-balancing swizzle for the 32KB h tile in LDS (r6/r7 proven).
static __device__ __forceinline__ int swzB(int B) {
  int pos = (B >> 4) & 127;
  int row = (B >> 11) & 15;
  int slot = (pos ^ row ^ (pos >> 3)) & 7;
  int npos = (pos & 0x78) | slot;
  return (B & ~0x7F0) | (npos << 4);
}

// ---------- fused pre-pass: embed + 4 transposes + mask in ONE launch ----------
// block ranges: [0,512) embed; [512,2560) Wx; [2560,6656) Wh; [6656,7680) W1;
// [7680,39680) W2; 39680 mask. Removes 5 launch gaps vs separate kernels.
__global__ void prepass_kernel(const int* __restrict__ inputs,
                               const float* __restrict__ emb,
                               u16* __restrict__ xbf,
                               const float* __restrict__ Wx, u16* __restrict__ Wxt,
                               const float* __restrict__ Wh, u16* __restrict__ Wht,
                               const float* __restrict__ W1, u16* __restrict__ W1t,
                               const float* __restrict__ W2, u16* __restrict__ W2t,
                               u64* __restrict__ mb) {
  __shared__ float t[32][33];
  int b = blockIdx.x;

  if (b < 512) {                       // ---- embed: xbf[row][e] = bf16(emb[tok][e])
    int i = b * 256 + threadIdx.x;     // 131072 threads
    int row = i >> 6;
    int e0 = (i & 63) << 3;
    int tok = inputs[row];
    const float* src = emb + (size_t)tok * 512 + e0;
    s16x8 o;
#pragma unroll
    for (int j = 0; j < 8; ++j) o[j] = (short)f2bf(src[j]);
    *(s16x8*)(xbf + (size_t)row * 512 + e0) = o;
    return;
  }

  if (b == 39680) {                    // ---- mask bit-pack
    int tq = threadIdx.x;
    if (tq < 32) {
      int bb = tq >> 1, h = tq & 1;
      u64 m = 0;
      for (int j = 0; j < 64; ++j)
        m |= (u64)(inputs[bb * 128 + h * 64 + j] != 0) << j;
      mb[tq] = m;
    }
    return;
  }

  // ---- transpose tile: Wt[n][k] = bf16(W[k][n])
  const float* W; u16* Wt; int K, N, tt;
  if (b < 2560)      { W = Wx; Wt = Wxt; K = 512;  N = 4096;  tt = b - 512;  }
  else if (b < 6656) { W = Wh; Wt = Wht; K = 1024; N = 4096;  tt = b - 2560; }
  else if (b < 7680) { W = W1; Wt = W1t; K = 1024; N = 1024;  tt = b - 6656; }
  else               { W = W2; Wt = W2t; K = 1024; N = 32000; tt = b - 7680; }
  int ntn = N >> 5;
  int tn = tt % ntn, tk = tt / ntn;
  int n0 = tn << 5, k0 = tk << 5;
  int tx = threadIdx.x & 31, ty = threadIdx.x >> 5;  // ty 0..7
#pragma unroll
  for (int j = 0; j < 4; ++j) {
    int k = ty * 4 + j;
    t[k][tx] = W[(size_t)(k0 + k) * N + n0 + tx];
  }
  __syncthreads();
#pragma unroll
  for (int j = 0; j < 4; ++j) {
    int n = ty * 4 + j;
    Wt[(size_t)(n0 + n) * K + k0 + tx] = f2bf(t[tx][n]);
  }
}

// ---------- m97-style bf16 GEMM, 128x128 tile, BK=32 ----------
// MODE 0: C=f32, store acc+bias          (xg)
// MODE 1: C=bf16, store relu(acc+bias)   (d1)
// MODE 2: C=f32, store exp(acc+bias), atomicAdd row sums (fallback path)
template <int MODE>
__global__ __launch_bounds__(256)
void gemm_bf16(const u16* __restrict__ A, const u16* __restrict__ Bt,
               const float* __restrict__ bias, void* __restrict__ Cptr,
               float* __restrict__ rowsum, int M, int N, int K) {
  (void)M;
  __shared__ u16 sA[128 * 32];
  __shared__ u16 sB[128 * 32];
  const int nbn = N >> 7;
  const int nwg = gridDim.x;
  int bid = blockIdx.x;
  int q = nwg >> 3;                         // grids are multiples of 8
  int swz = (bid & 7) * q + (bid >> 3);     // XCD-aware swizzle (bijective)
  int bm = swz / nbn, bn = swz % nbn;
  const int brow = bm << 7, bcol = bn << 7;

  const int tid = threadIdx.x;
  const int lane = tid & 63;
  const int wv = tid >> 6;
  const int wr = (wv >> 1) * 64, wc = (wv & 1) * 64;
  const int ln = lane & 15, kh = lane >> 4;

  const int srow = tid >> 2;                // 0..63
  const int kch = (tid & 3) << 3;           // 0,8,16,24 (elements)

  f32x4 acc[4][4] = {};

  const int nk = K >> 5;
  const u16* Abase = A + (size_t)(brow + srow) * K + kch;
  const u16* Bbase = Bt + (size_t)(bcol + srow) * K + kch;
  const size_t rstride = (size_t)64 * K;
  u16* lA = sA + srow * 32 + kch;
  u16* lB = sB + srow * 32 + kch;

  for (int kt = 0; kt < nk; ++kt) {
    const int k0 = kt << 5;
    gload_lds16(Abase + k0, lA);
    gload_lds16(Abase + rstride + k0, lA + 64 * 32);
    gload_lds16(Bbase + k0, lB);
    gload_lds16(Bbase + rstride + k0, lB + 64 * 32);
    __syncthreads();
    s16x8 aF[4], bF[4];
#pragma unroll
    for (int m = 0; m < 4; ++m)
      aF[m] = *(const s16x8*)(sA + (wr + m * 16 + ln) * 32 + kh * 8);
#pragma unroll
    for (int n = 0; n < 4; ++n)
      bF[n] = *(const s16x8*)(sB + (wc + n * 16 + ln) * 32 + kh * 8);
#pragma unroll
    for (int m = 0; m < 4; ++m)
#pragma unroll
      for (int n = 0; n < 4; ++n)
        acc[m][n] = __builtin_amdgcn_mfma_f32_16x16x32_bf16(aF[m], bF[n], acc[m][n], 0, 0, 0);
    __syncthreads();
  }

  const int browq = brow + wr;
  const int bcolq = bcol + wc;

  if (MODE == 1) {
    u16* O = (u16*)Cptr;
#pragma unroll
    for (int n = 0; n < 4; ++n) {
      int gcol = bcolq + n * 16 + ln;
      float bv = bias[gcol];
#pragma unroll
      for (int m = 0; m < 4; ++m)
#pragma unroll
        for (int r = 0; r < 4; ++r) {
          int grow = browq + m * 16 + kh * 4 + r;
          float v = fmaxf(acc[m][n][r] + bv, 0.f);
          O[(size_t)grow * N + gcol] = f2bf(v);
        }
    }
  } else {
    float* O = (float*)Cptr;
    float rs[4][4] = {};
#pragma unroll
    for (int n = 0; n < 4; ++n) {
      int gcol = bcolq + n * 16 + ln;
      float bv = bias[gcol];
#pragma unroll
      for (int m = 0; m < 4; ++m)
#pragma unroll
        for (int r = 0; r < 4; ++r) {
          int grow = browq + m * 16 + kh * 4 + r;
          float v = acc[m][n][r] + bv;
          if (MODE == 2) { v = __expf(v); rs[m][r] += v; }
          O[(size_t)grow * N + gcol] = v;
        }
    }
    if (MODE == 2) {
#pragma unroll
      for (int m = 0; m < 4; ++m)
#pragma unroll
        for (int r = 0; r < 4; ++r) {
          float v = rs[m][r];
          v += __shfl_xor(v, 1);
          v += __shfl_xor(v, 2);
          v += __shfl_xor(v, 4);
          v += __shfl_xor(v, 8);
          if (ln == 0) atomicAdd(&rowsum[browq + m * 16 + kh * 4 + r], v);
        }
    }
  }
}

// ---------- 256x256-tile logits GEMM, counted-vmcnt 4-buffer pipeline ----------
// Proven r12 depth-2 (r16's depth-3 was noise-negative): 2 tiles in flight,
// vmcnt(4) per iter (never 0 until tail), ONE barrier/iter. Frag-read banking
// already balanced at the b128 BW floor (8/bank). Fused exp epilogue.
__global__ __launch_bounds__(512, 1)
void gemm256_exp(const u16* __restrict__ A, const u16* __restrict__ Bt,
                 const float* __restrict__ bias, u16* __restrict__ O,
                 float* __restrict__ rowsum, int M, int N, int K) {
  (void)M;
  __shared__ char lds[131072];              // 4 bufs x 32KB
  const int nbn = N >> 8;                   // 125
  const int nwg = gridDim.x;                // 1000 (multiple of 8)
  int bid = blockIdx.x;
  int q = nwg >> 3;
  int swz = (bid & 7) * q + (bid >> 3);     // XCD swizzle (bijective)
  int bm = swz / nbn, bn = swz % nbn;
  const int brow = bm << 8, bcol = bn << 8;

  const int tid = threadIdx.x;
  const int lane = tid & 63;
  const int wv = tid >> 6;                  // 0..7
  const int wm = wv >> 2, wn = wv & 3;
  const int ln = lane & 15, kh = lane >> 4;

  const int nk = K >> 5;                    // 32

  const u16* sbase[4];
#pragma unroll
  for (int j = 0; j < 4; ++j) {
    int cc = (j & 1) * 512 + wv * 64 + lane;
    int row = cc >> 2, pcol = cc & 3;
    int lcol = pcol ^ ((row >> 1) & 3);
    sbase[j] = (j < 2 ? A + (size_t)(brow + row) * K
                      : Bt + (size_t)(bcol + row) * K) + lcol * 8;
  }

#define STAGE256(kt, buf)                                                  \
  {                                                                        \
    char* lb = lds + (buf) * 32768 + wv * 1024;                            \
    _Pragma("unroll")                                                      \
    for (int j = 0; j < 4; ++j)                                            \
      gload_lds16(sbase[j] + (kt) * 32, lb + j * 8192);                    \
  }

  f32x4 acc[8][4] = {};

  STAGE256(0, 0);
  STAGE256(1, 1);
  asm volatile("s_waitcnt vmcnt(4)" ::: "memory");   // tile 0 landed
  __syncthreads();

  const char* Ab = lds + (size_t)(wm * 128) * 64;
  const char* Bb = lds + 16384 + (size_t)(wn * 64) * 64;
  const int cswz = (kh ^ ((ln >> 1) & 3)) * 16 + ln * 64;

  for (int t = 0; t < nk; ++t) {
    const int boff = (t & 3) * 32768;
    if (t + 2 < nk) STAGE256(t + 2, (t + 2) & 3);
    s16x8 aF[8], bF[4];
#pragma unroll
    for (int m = 0; m < 8; ++m)
      aF[m] = *(const s16x8*)(Ab + boff + m * 1024 + cswz);
#pragma unroll
    for (int n = 0; n < 4; ++n)
      bF[n] = *(const s16x8*)(Bb + boff + n * 1024 + cswz);
    __builtin_amdgcn_s_setprio(1);
#pragma unroll
    for (int m = 0; m < 8; ++m)
#pragma unroll
      for (int n = 0; n < 4; ++n)
        acc[m][n] = __builtin_amdgcn_mfma_f32_16x16x32_bf16(aF[m], bF[n], acc[m][n], 0, 0, 0);
    __builtin_amdgcn_s_setprio(0);
    if (t + 2 < nk)
      asm volatile("s_waitcnt vmcnt(4)" ::: "memory");   // tile t+1 landed
    else
      asm volatile("s_waitcnt vmcnt(0)" ::: "memory");   // drain tail
    if (t < nk - 1) __syncthreads();
  }

  // ---- fused softmax-exp epilogue ----
  const int browq = brow + wm * 128;
  const int bcolq = bcol + wn * 64;
  float rs[8][4] = {};
#pragma unroll
  for (int n = 0; n < 4; ++n) {
    int gcol = bcolq + n * 16 + ln;
    float bv = bias[gcol];
#pragma unroll
    for (int m = 0; m < 8; ++m)
#pragma unroll
      for (int r = 0; r < 4; ++r) {
        float v = __expf(acc[m][n][r] + bv);
        rs[m][r] += v;
        O[(size_t)(browq + m * 16 + kh * 4 + r) * N + gcol] = f2bf(v);
      }
  }
#pragma unroll
  for (int m = 0; m < 8; ++m)
#pragma unroll
    for (int r = 0; r < 4; ++r) {
      float v = rs[m][r];
      v += __shfl_xor(v, 1);
      v += __shfl_xor(v, 2);
      v += __shfl_xor(v, 4);
      v += __shfl_xor(v, 8);
      if (ln == 0) atomicAdd(&rowsum[browq + m * 16 + kh * 4 + r], v);
    }
#undef STAGE256
}

// ---------- persistent LSTM: 32 WGs x 512 threads, full-K waves ----------
// Best measured config (r11/r12, 484us) — unchanged. Ledger: sync mechanism
// (r2-r4, r8-r10), B-residency (r13-r14), LDS-A-path (r15) all falsified as
// dominant costs; per-step 3.78us = serialized fabric RTs (publish-drain,
// arrive, observe, stage) at this recurrence structure's floor.
__global__ __launch_bounds__(512, 1)
void lstm_kernel(const float* __restrict__ xg,      // [2048][4096] f32
                 const u16* __restrict__ Wht,       // [4096][1024] bf16 (n-major)
                 const u64* __restrict__ maskb,     // [16][2] bitmask
                 const float* __restrict__ ench, const float* __restrict__ encc,
                 const float* __restrict__ gamma, const float* __restrict__ beta,
                 const float* __restrict__ mmean, const float* __restrict__ mvar,
                 u32* __restrict__ hbuf32,          // [2][16][512] u32 (linear)
                 u16* __restrict__ hbn,             // [2048][1024] bf16 out
                 u32* __restrict__ cnt) {
  __shared__ char hA[32 * 1024];       // staged h(s), swzB-swizzled

  const int wg = blockIdx.x;           // 0..31
  const int u0 = wg << 5;              // 32 units per WG
  const int tid = threadIdx.x;
  const int lane = tid & 63;
  const int wv = tid >> 6;             // 0..7
  const int ln = lane & 15, khq = lane >> 4;

  const int g = ln & 3;                // gate index (i,f,cc,o)
  const int unit = u0 + wv * 4 + (ln >> 2);

  // ---- Wh preload: 32 x 16B via inline asm ----
  u32x4 bWq[32];
  {
    const u16* wrow = Wht + (size_t)(g * 1024 + unit) * 1024 + khq * 8;
#pragma unroll
    for (int kt = 0; kt < 32; ++kt) {
      const u16* pp = wrow + kt * 32;
      asm volatile("global_load_dwordx4 %0, %1, off" : "=v"(bWq[kt]) : "v"(pp));
    }
    asm volatile("s_waitcnt vmcnt(0)" ::: "memory");
  }

  // per-lane state (g==0 lanes meaningful after shfl combine)
  float cellR[4], holdR[4], xgr[4];
  u64 mA[4], mB[4];
  const float bn_s = gamma[unit] * rsqrtf(mvar[unit] + 1e-3f);
  const float bn_b = beta[unit] - mmean[unit] * bn_s;
  const size_t bstride = (size_t)128 * 4096;
  const float* xbase = xg + (size_t)(khq * 4) * bstride + g * 1024 + unit;
#pragma unroll
  for (int r = 0; r < 4; ++r) {
    int batch = khq * 4 + r;
    cellR[r] = encc[batch * 1024 + unit];
    holdR[r] = ench[batch * 1024 + unit];
    mA[r] = maskb[batch * 2];
    mB[r] = maskb[batch * 2 + 1];
  }
  // initial publish of h(0) into parity-0 buffer
#pragma unroll
  for (int r = 0; r < 4; ++r) {
    u32 w = (u32)f2bf(holdR[r]);
    u32 pw = (u32)__shfl_xor((int)w, 4);   // partner unit+1, same gate
    if ((ln & 7) == 0) {
      int batch = khq * 4 + r;
      AT_ST((u32*)((char*)hbuf32 + batch * 2048 + unit * 2), (w & 0xFFFFu) | (pw << 16));
    }
  }
#pragma unroll
  for (int r = 0; r < 4; ++r) xgr[r] = xbase[r * bstride];   // xg(0) prefetch
  asm volatile("s_waitcnt vmcnt(0)" ::: "memory");
  __syncthreads();
  if (tid == 0) {
    u32 oldv = AT_FAA(cnt);
    if (oldv != 31u) {
      int c = 0;
      while (AT_LD((const u32*)cnt) < 32u) {
        __builtin_amdgcn_s_sleep(1);
        if (++c > (1 << 18)) break;
      }
    }
  }
  __syncthreads();

  for (int s = 0; s < 128; ++s) {
    // ---- stage h(s): 8 back-to-back uncached u64 loads, one waitcnt ----
    u64 st[8];
    {
      const u64* base = (const u64*)((const char*)hbuf32 + (s & 1) * 32768) + tid;
#pragma unroll
      for (int k = 0; k < 8; ++k) {
        const u64* pp = base + k * 512;
        asm volatile("global_load_dwordx2 %0, %1, off sc0 sc1" : "=v"(st[k]) : "v"(pp));
      }
      asm volatile("s_waitcnt vmcnt(0)" ::: "memory");
      __builtin_amdgcn_sched_barrier(0);
#pragma unroll
      for (int k = 0; k < 8; ++k)
        *(u64*)(hA + swzB((tid + k * 512) * 8)) = st[k];
    }
    __syncthreads();                           // (A) hA ready

    // ---- 32 MFMA over full K, 2 chains; A from LDS ----
    f32x4 acc0 = {0.f, 0.f, 0.f, 0.f};
    f32x4 acc1 = {0.f, 0.f, 0.f, 0.f};
#pragma unroll
    for (int kt = 0; kt < 32; kt += 2) {
      s16x8 a0 = *(const s16x8*)(hA + swzB(ln * 2048 + kt * 64 + khq * 16));
      acc0 = __builtin_amdgcn_mfma_f32_16x16x32_bf16(
          a0, __builtin_bit_cast(s16x8, bWq[kt]), acc0, 0, 0, 0);
      s16x8 a1 = *(const s16x8*)(hA + swzB(ln * 2048 + (kt + 1) * 64 + khq * 16));
      acc1 = __builtin_amdgcn_mfma_f32_16x16x32_bf16(
          a1, __builtin_bit_cast(s16x8, bWq[kt + 1]), acc1, 0, 0, 0);
    }
    f32x4 accs = acc0 + acc1;

    // ---- gates fully in-wave (lane quads hold i,f,cc,o) + publish ----
    u32 bnpair[4];
    {
      u16 hbb[4], hbnb[4];
#pragma unroll
      for (int r = 0; r < 4; ++r) {
        float z = accs[r] + xgr[r];
        float sig = 1.f / (1.f + __expf(-z));
        float val = (g == 2) ? fmaxf(z, 0.f) : sig;
        float v1 = __shfl_xor(val, 1);
        float v2 = __shfl_xor(val, 2);
        float v3 = __shfl_xor(val, 3);
        float cnew = v1 * cellR[r] + val * v2;   // f*c + i*cc (g==0 view)
        float hnew = v3 * fmaxf(cnew, 0.f);
        u64 mm = (s < 64) ? mA[r] : mB[r];
        if (!((mm >> (s & 63)) & 1)) { cnew = cellR[r]; hnew = holdR[r]; }
        cellR[r] = cnew;
        holdR[r] = hnew;
        hbb[r] = f2bf(hnew);
        hbnb[r] = f2bf(hnew * bn_s + bn_b);
      }
#pragma unroll
      for (int r = 0; r < 4; ++r) {
        u32 w = (u32)hbb[r] | ((u32)hbnb[r] << 16);
        u32 pw = (u32)__shfl_xor((int)w, 4);
        u32 hpair = (w & 0xFFFFu) | ((pw & 0xFFFFu) << 16);
        bnpair[r] = (w >> 16) | (pw & 0xFFFF0000u);
        if (s < 127 && (ln & 7) == 0) {
          int batch = khq * 4 + r;
          AT_ST((u32*)((char*)hbuf32 + ((s + 1) & 1) * 32768 + batch * 2048 + unit * 2), hpair);
        }
      }
    }

    if (s < 127) {
      asm volatile("s_waitcnt vmcnt(0)" ::: "memory");   // drain h publishes
      __syncthreads();                         // (B) all publishes complete
      u32 oldv = 0xFFFFFFFFu;
      if (tid == 0) oldv = AT_FAA(cnt);
      // deferred hbn stores + xg(s+1) prefetch overlap the poll
      if ((ln & 7) == 0) {
#pragma unroll
        for (int r = 0; r < 4; ++r) {
          int batch = khq * 4 + r;
          *(u32*)((char*)hbn + (size_t)(batch * 128 + s) * 2048 + unit * 2) = bnpair[r];
        }
      }
      {
        const float* xb = xbase + (size_t)(s + 1) * 4096;
#pragma unroll
        for (int r = 0; r < 4; ++r) xgr[r] = xb[r * bstride];
      }
      if (tid == 0) {
        const u32 target = (u32)(s + 2) * 32u;
        if (oldv != target - 1u) {
          int c = 0;
          while (AT_LD((const u32*)cnt) < target) {
            __builtin_amdgcn_s_sleep(1);
            if (++c > (1 << 18)) break;
          }
        }
      }
      __syncthreads();                         // (C) release
    } else if ((ln & 7) == 0) {
      // s == 127: final hbn stores
#pragma unroll
      for (int r = 0; r < 4; ++r) {
        int batch = khq * 4 + r;
        *(u32*)((char*)hbn + (size_t)(batch * 128 + s) * 2048 + unit * 2) = bnpair[r];
      }
    }
  }
}

// ---------- softmax finish ----------

// f32 path (fallback): in-place scale of f32 exp
__global__ void scale_kernel(float* __restrict__ out, const float* __restrict__ rs) {
  const int total4 = 16384000;              // 65,536,000 / 4
  for (int i = blockIdx.x * 256 + threadIdx.x; i < total4; i += gridDim.x * 256) {
    float4* p = (float4*)out + i;
    float4 v = *p;
    int row = i / 8000;                     // 8000 float4 per row
    float sF = 1.0f / rs[row];
    v.x *= sF; v.y *= sF; v.z *= sF; v.w *= sF;
    *p = v;
  }
}

// bf16 path: ONE ROW PER BLOCK (2048 blocks) — no division, rowsum broadcast
// once, fully coalesced row-contiguous access. 4000 s16x8 groups per row.
__global__ __launch_bounds__(256)
void scale_bf_kernel(float* __restrict__ out, const u16* __restrict__ e,
                     const float* __restrict__ rs) {
  const int row = blockIdx.x;               // 0..2047
  const float sF = 1.0f / rs[row];
  const s16x8* src = (const s16x8*)(e + (size_t)row * 32000);
  float4* dst = (float4*)(out + (size_t)row * 32000);
  for (int i = threadIdx.x; i < 4000; i += 256) {
    s16x8 v = src[i];
    float4 o0, o1;
    o0.x = bf2f((u16)v[0]) * sF; o0.y = bf2f((u16)v[1]) * sF;
    o0.z = bf2f((u16)v[2]) * sF; o0.w = bf2f((u16)v[3]) * sF;
    o1.x = bf2f((u16)v[4]) * sF; o1.y = bf2f((u16)v[5]) * sF;
    o1.z = bf2f((u16)v[6]) * sF; o1.w = bf2f((u16)v[7]) * sF;
    dst[2 * i] = o0;
    dst[2 * i + 1] = o1;
  }
}

// ---------- launch ----------

extern "C" void kernel_launch(void* const* d_in, const int* in_sizes, int n_in,
                              void* d_out, int out_size, void* d_ws, size_t ws_size,
                              hipStream_t stream) {
  (void)in_sizes; (void)n_in; (void)out_size;
  const int*   inputs = (const int*)d_in[0];
  const float* ench   = (const float*)d_in[1];
  const float* encc   = (const float*)d_in[2];
  const float* emb    = (const float*)d_in[3];
  const float* Wx     = (const float*)d_in[4];
  const float* Wh     = (const float*)d_in[5];
  const float* bb     = (const float*)d_in[6];
  const float* gamma  = (const float*)d_in[7];
  const float* beta   = (const float*)d_in[8];
  const float* mmean  = (const float*)d_in[9];
  const float* mvar   = (const float*)d_in[10];
  const float* W1     = (const float*)d_in[11];
  const float* b1     = (const float*)d_in[12];
  const float* W2     = (const float*)d_in[13];
  const float* b2     = (const float*)d_in[14];
  float* out = (float*)d_out;

  char* p = (char*)d_ws;
  u32*   cnt    = (u32*)(p + 0);            // word 0
  float* rowsum = (float*)(p + 1024);       // 2048 floats; memset covers [0,9216)
  u64*   maskb  = (u64*)(p + 10240);        // 256B, written by prepass
  u32*   hbuf32 = (u32*)(p + 16384);        // 64KB (2 x 32KB parity tiles)
  size_t off = 81920;
  u16*   xbf  = (u16*)(p + off);     off += (size_t)2048 * 512 * 2;     // 2MB
  u16*   Wxt  = (u16*)(p + off);     off += (size_t)4096 * 512 * 2;     // 4MB
  u16*   Wht  = (u16*)(p + off);     off += (size_t)4096 * 1024 * 2;    // 8MB
  u16*   W1t  = (u16*)(p + off);     off += (size_t)1024 * 1024 * 2;    // 2MB
  u16*   W2t  = (u16*)(p + off);     off += (size_t)32000 * 1024 * 2;   // 64MB
  float* xg   = (float*)(p + off);   off += (size_t)2048 * 4096 * 4;    // 32MB
  u16*   hbn  = (u16*)(p + off);     off += (size_t)2048 * 1024 * 2;    // 4MB
  u16*   d1   = (u16*)(p + off);     off += (size_t)2048 * 1024 * 2;    // 4MB
  size_t off_base = off;
  u16*   expbf = (u16*)(p + off);    off += (size_t)2048 * 32000 * 2;   // 125MB (optional)
  if (ws_size < off_base) return;  // insufficient scratch; avoid OOB
  const bool bf16path = (ws_size >= off);

  hipMemsetAsync(d_ws, 0, 9216, stream);  // cnt + rowsum

  // fused pre-pass: embed (512) + Wx/Wh/W1/W2 transposes (38656) + mask (1)
  prepass_kernel<<<39681, 256, 0, stream>>>(inputs, emb, xbf, Wx, Wxt, Wh, Wht,
                                            W1, W1t, W2, W2t, maskb);

  gemm_bf16<0><<<16 * 32, 256, 0, stream>>>(xbf, Wxt, bb, xg, nullptr, 2048, 4096, 512);

  lstm_kernel<<<32, 512, 0, stream>>>(xg, Wht, maskb, ench, encc, gamma, beta,
                                      mmean, mvar, hbuf32, hbn, cnt);

  gemm_bf16<1><<<16 * 8, 256, 0, stream>>>(hbn, W1t, b1, d1, nullptr, 2048, 1024, 1024);

  if (bf16path) {
    gemm256_exp<<<8 * 125, 512, 0, stream>>>(d1, W2t, b2, expbf, rowsum, 2048, 32000, 1024);
    scale_bf_kernel<<<2048, 256, 0, stream>>>(out, expbf, rowsum);
  } else {
    gemm_bf16<2><<<16 * 250, 256, 0, stream>>>(d1, W2t, b2, out, rowsum, 2048, 32000, 1024);
    scale_kernel<<<2048, 256, 0, stream>>>(out, rowsum);
  }
}

// Round 18
// 846.637 us; speedup vs baseline: 1.1948x; 1.0477x over previous
//
#include <hip/hip_runtime.h>
#include <hip/hip_bf16.h>
#include <stdint.h>

typedef unsigned short u16;
typedef unsigned int u32;
typedef unsigned long long u64;
typedef __attribute__((ext_vector_type(4))) float f32x4;
typedef __attribute__((ext_vector_type(8))) short s16x8;
typedef __attribute__((ext_vector_type(4))) unsigned int u32x4;

#define AT_LD(p)    __hip_atomic_load((p), __ATOMIC_RELAXED, __HIP_MEMORY_SCOPE_AGENT)
#define AT_ST(p, v) __hip_atomic_store((p), (v), __ATOMIC_RELAXED, __HIP_MEMORY_SCOPE_AGENT)
#define AT_FAA(p)   __hip_atomic_fetch_add((p), 1u, __ATOMIC_RELAXED, __HIP_MEMORY_SCOPE_AGENT)

// ---------- helpers ----------

static __device__ __forceinline__ u16 f2bf(float f) {
  union { float f; unsigned u; } v; v.f = f;
  unsigned r = v.u + 0x7FFFu + ((v.u >> 16) & 1u);
  return (u16)(r >> 16);
}

static __device__ __forceinline__ float bf2f(u16 b) {
  union { unsigned u; float f; } v; v.u = ((u32)b) << 16;
  return v.f;
}

static __device__ __forceinline__ void gload_lds16(const void* g, void* l) {
  __builtin_amdgcn_global_load_lds(
      (const __attribute__((address_space(1))) unsigned int*)(uintptr_t)g,
      (__attribute__((address_space(3))) unsigned int*)(uintptr_t)l,
      16, 0, 0);
}

// bank-balancing swizzle for the 32KB h tile in LDS (r6/r7 proven).
static __device__ __forceinline__ int swzB(int B) {
  int pos = (B >> 4) & 127;
  int row = (B >> 11) & 15;
  int slot = (pos ^ row ^ (pos >> 3)) & 7;
  int npos = (pos & 0x78) | slot;
  return (B & ~0x7F0) | (npos << 4);
}

// ---------- pre-pass (embed + Wx + Wh transposes + mask) ----------
// block ranges: [0,512) embed; [512,2560) Wx; [2560,6656) Wh; 6656 mask.
// W1/W2 transposes moved into the LSTM launch (hidden under its 484us on
// the 224 idle CUs).
__global__ void prepass_kernel(const int* __restrict__ inputs,
                               const float* __restrict__ emb,
                               u16* __restrict__ xbf,
                               const float* __restrict__ Wx, u16* __restrict__ Wxt,
                               const float* __restrict__ Wh, u16* __restrict__ Wht,
                               u64* __restrict__ mb) {
  __shared__ float t[32][33];
  int b = blockIdx.x;

  if (b < 512) {                       // ---- embed
    int i = b * 256 + threadIdx.x;
    int row = i >> 6;
    int e0 = (i & 63) << 3;
    int tok = inputs[row];
    const float* src = emb + (size_t)tok * 512 + e0;
    s16x8 o;
#pragma unroll
    for (int j = 0; j < 8; ++j) o[j] = (short)f2bf(src[j]);
    *(s16x8*)(xbf + (size_t)row * 512 + e0) = o;
    return;
  }

  if (b == 6656) {                     // ---- mask bit-pack
    int tq = threadIdx.x;
    if (tq < 32) {
      int bb = tq >> 1, h = tq & 1;
      u64 m = 0;
      for (int j = 0; j < 64; ++j)
        m |= (u64)(inputs[bb * 128 + h * 64 + j] != 0) << j;
      mb[tq] = m;
    }
    return;
  }

  // ---- transpose tile: Wt[n][k] = bf16(W[k][n])
  const float* W; u16* Wt; int K, N, tt;
  if (b < 2560) { W = Wx; Wt = Wxt; K = 512;  N = 4096; tt = b - 512;  }
  else          { W = Wh; Wt = Wht; K = 1024; N = 4096; tt = b - 2560; }
  int ntn = N >> 5;
  int tn = tt % ntn, tk = tt / ntn;
  int n0 = tn << 5, k0 = tk << 5;
  int tx = threadIdx.x & 31, ty = threadIdx.x >> 5;  // ty 0..7
#pragma unroll
  for (int j = 0; j < 4; ++j) {
    int k = ty * 4 + j;
    t[k][tx] = W[(size_t)(k0 + k) * N + n0 + tx];
  }
  __syncthreads();
#pragma unroll
  for (int j = 0; j < 4; ++j) {
    int n = ty * 4 + j;
    Wt[(size_t)(n0 + n) * K + k0 + tx] = f2bf(t[tx][n]);
  }
}

// ---------- m97-style bf16 GEMM, 128x128 tile, BK=32 ----------
// MODE 0: C=f32, store acc+bias          (xg)
// MODE 1: C=bf16, store relu(acc+bias)   (d1)
// MODE 2: C=f32, store exp(acc+bias), atomicAdd row sums (fallback path)
template <int MODE>
__global__ __launch_bounds__(256)
void gemm_bf16(const u16* __restrict__ A, const u16* __restrict__ Bt,
               const float* __restrict__ bias, void* __restrict__ Cptr,
               float* __restrict__ rowsum, int M, int N, int K) {
  (void)M;
  __shared__ u16 sA[128 * 32];
  __shared__ u16 sB[128 * 32];
  const int nbn = N >> 7;
  const int nwg = gridDim.x;
  int bid = blockIdx.x;
  int q = nwg >> 3;                         // grids are multiples of 8
  int swz = (bid & 7) * q + (bid >> 3);     // XCD-aware swizzle (bijective)
  int bm = swz / nbn, bn = swz % nbn;
  const int brow = bm << 7, bcol = bn << 7;

  const int tid = threadIdx.x;
  const int lane = tid & 63;
  const int wv = tid >> 6;
  const int wr = (wv >> 1) * 64, wc = (wv & 1) * 64;
  const int ln = lane & 15, kh = lane >> 4;

  const int srow = tid >> 2;                // 0..63
  const int kch = (tid & 3) << 3;           // 0,8,16,24 (elements)

  f32x4 acc[4][4] = {};

  const int nk = K >> 5;
  const u16* Abase = A + (size_t)(brow + srow) * K + kch;
  const u16* Bbase = Bt + (size_t)(bcol + srow) * K + kch;
  const size_t rstride = (size_t)64 * K;
  u16* lA = sA + srow * 32 + kch;
  u16* lB = sB + srow * 32 + kch;

  for (int kt = 0; kt < nk; ++kt) {
    const int k0 = kt << 5;
    gload_lds16(Abase + k0, lA);
    gload_lds16(Abase + rstride + k0, lA + 64 * 32);
    gload_lds16(Bbase + k0, lB);
    gload_lds16(Bbase + rstride + k0, lB + 64 * 32);
    __syncthreads();
    s16x8 aF[4], bF[4];
#pragma unroll
    for (int m = 0; m < 4; ++m)
      aF[m] = *(const s16x8*)(sA + (wr + m * 16 + ln) * 32 + kh * 8);
#pragma unroll
    for (int n = 0; n < 4; ++n)
      bF[n] = *(const s16x8*)(sB + (wc + n * 16 + ln) * 32 + kh * 8);
#pragma unroll
    for (int m = 0; m < 4; ++m)
#pragma unroll
      for (int n = 0; n < 4; ++n)
        acc[m][n] = __builtin_amdgcn_mfma_f32_16x16x32_bf16(aF[m], bF[n], acc[m][n], 0, 0, 0);
    __syncthreads();
  }

  const int browq = brow + wr;
  const int bcolq = bcol + wc;

  if (MODE == 1) {
    u16* O = (u16*)Cptr;
#pragma unroll
    for (int n = 0; n < 4; ++n) {
      int gcol = bcolq + n * 16 + ln;
      float bv = bias[gcol];
#pragma unroll
      for (int m = 0; m < 4; ++m)
#pragma unroll
        for (int r = 0; r < 4; ++r) {
          int grow = browq + m * 16 + kh * 4 + r;
          float v = fmaxf(acc[m][n][r] + bv, 0.f);
          O[(size_t)grow * N + gcol] = f2bf(v);
        }
    }
  } else {
    float* O = (float*)Cptr;
    float rs[4][4] = {};
#pragma unroll
    for (int n = 0; n < 4; ++n) {
      int gcol = bcolq + n * 16 + ln;
      float bv = bias[gcol];
#pragma unroll
      for (int m = 0; m < 4; ++m)
#pragma unroll
        for (int r = 0; r < 4; ++r) {
          int grow = browq + m * 16 + kh * 4 + r;
          float v = acc[m][n][r] + bv;
          if (MODE == 2) { v = __expf(v); rs[m][r] += v; }
          O[(size_t)grow * N + gcol] = v;
        }
    }
    if (MODE == 2) {
#pragma unroll
      for (int m = 0; m < 4; ++m)
#pragma unroll
        for (int r = 0; r < 4; ++r) {
          float v = rs[m][r];
          v += __shfl_xor(v, 1);
          v += __shfl_xor(v, 2);
          v += __shfl_xor(v, 4);
          v += __shfl_xor(v, 8);
          if (ln == 0) atomicAdd(&rowsum[browq + m * 16 + kh * 4 + r], v);
        }
    }
  }
}

// ---------- 256x256-tile logits GEMM, counted-vmcnt 4-buffer pipeline ----------
// Proven r12 depth-2: 2 tiles in flight, vmcnt(4) per iter, ONE barrier/iter.
__global__ __launch_bounds__(512, 1)
void gemm256_exp(const u16* __restrict__ A, const u16* __restrict__ Bt,
                 const float* __restrict__ bias, u16* __restrict__ O,
                 float* __restrict__ rowsum, int M, int N, int K) {
  (void)M;
  __shared__ char lds[131072];              // 4 bufs x 32KB
  const int nbn = N >> 8;                   // 125
  const int nwg = gridDim.x;                // 1000 (multiple of 8)
  int bid = blockIdx.x;
  int q = nwg >> 3;
  int swz = (bid & 7) * q + (bid >> 3);     // XCD swizzle (bijective)
  int bm = swz / nbn, bn = swz % nbn;
  const int brow = bm << 8, bcol = bn << 8;

  const int tid = threadIdx.x;
  const int lane = tid & 63;
  const int wv = tid >> 6;                  // 0..7
  const int wm = wv >> 2, wn = wv & 3;
  const int ln = lane & 15, kh = lane >> 4;

  const int nk = K >> 5;                    // 32

  const u16* sbase[4];
#pragma unroll
  for (int j = 0; j < 4; ++j) {
    int cc = (j & 1) * 512 + wv * 64 + lane;
    int row = cc >> 2, pcol = cc & 3;
    int lcol = pcol ^ ((row >> 1) & 3);
    sbase[j] = (j < 2 ? A + (size_t)(brow + row) * K
                      : Bt + (size_t)(bcol + row) * K) + lcol * 8;
  }

#define STAGE256(kt, buf)                                                  \
  {                                                                        \
    char* lb = lds + (buf) * 32768 + wv * 1024;                            \
    _Pragma("unroll")                                                      \
    for (int j = 0; j < 4; ++j)                                            \
      gload_lds16(sbase[j] + (kt) * 32, lb + j * 8192);                    \
  }

  f32x4 acc[8][4] = {};

  STAGE256(0, 0);
  STAGE256(1, 1);
  asm volatile("s_waitcnt vmcnt(4)" ::: "memory");   // tile 0 landed
  __syncthreads();

  const char* Ab = lds + (size_t)(wm * 128) * 64;
  const char* Bb = lds + 16384 + (size_t)(wn * 64) * 64;
  const int cswz = (kh ^ ((ln >> 1) & 3)) * 16 + ln * 64;

  for (int t = 0; t < nk; ++t) {
    const int boff = (t & 3) * 32768;
    if (t + 2 < nk) STAGE256(t + 2, (t + 2) & 3);
    s16x8 aF[8], bF[4];
#pragma unroll
    for (int m = 0; m < 8; ++m)
      aF[m] = *(const s16x8*)(Ab + boff + m * 1024 + cswz);
#pragma unroll
    for (int n = 0; n < 4; ++n)
      bF[n] = *(const s16x8*)(Bb + boff + n * 1024 + cswz);
    __builtin_amdgcn_s_setprio(1);
#pragma unroll
    for (int m = 0; m < 8; ++m)
#pragma unroll
      for (int n = 0; n < 4; ++n)
        acc[m][n] = __builtin_amdgcn_mfma_f32_16x16x32_bf16(aF[m], bF[n], acc[m][n], 0, 0, 0);
    __builtin_amdgcn_s_setprio(0);
    if (t + 2 < nk)
      asm volatile("s_waitcnt vmcnt(4)" ::: "memory");   // tile t+1 landed
    else
      asm volatile("s_waitcnt vmcnt(0)" ::: "memory");   // drain tail
    if (t < nk - 1) __syncthreads();
  }

  // ---- fused softmax-exp epilogue ----
  const int browq = brow + wm * 128;
  const int bcolq = bcol + wn * 64;
  float rs[8][4] = {};
#pragma unroll
  for (int n = 0; n < 4; ++n) {
    int gcol = bcolq + n * 16 + ln;
    float bv = bias[gcol];
#pragma unroll
    for (int m = 0; m < 8; ++m)
#pragma unroll
      for (int r = 0; r < 4; ++r) {
        float v = __expf(acc[m][n][r] + bv);
        rs[m][r] += v;
        O[(size_t)(browq + m * 16 + kh * 4 + r) * N + gcol] = f2bf(v);
      }
  }
#pragma unroll
  for (int m = 0; m < 8; ++m)
#pragma unroll
    for (int r = 0; r < 4; ++r) {
      float v = rs[m][r];
      v += __shfl_xor(v, 1);
      v += __shfl_xor(v, 2);
      v += __shfl_xor(v, 4);
      v += __shfl_xor(v, 8);
      if (ln == 0) atomicAdd(&rowsum[browq + m * 16 + kh * 4 + r], v);
    }
#undef STAGE256
}

// ---------- persistent LSTM (blocks 0..31) + W1/W2 transpose (blocks 32+) ----------
// LSTM part = best measured config (r11/r12, 484us), byte-identical. The W1/W2
// transposes ride along on the 224 idle CUs (LSTM occupies 32 CUs at 3% device
// occupancy) and finish in ~35us wall-clock, off the critical path. Stream
// ordering still guarantees W1t/W2t before gemm<1>/gemm256. Deadlock-safe:
// transpose blocks never wait, so they drain and free CUs for LSTM blocks;
// LSTM's entry poll tolerates ~8ms of dispatch skew.
__global__ __launch_bounds__(512, 1)
void lstm_kernel(const float* __restrict__ xg,      // [2048][4096] f32
                 const u16* __restrict__ Wht,       // [4096][1024] bf16 (n-major)
                 const u64* __restrict__ maskb,     // [16][2] bitmask
                 const float* __restrict__ ench, const float* __restrict__ encc,
                 const float* __restrict__ gamma, const float* __restrict__ beta,
                 const float* __restrict__ mmean, const float* __restrict__ mvar,
                 u32* __restrict__ hbuf32,          // [2][16][512] u32 (linear)
                 u16* __restrict__ hbn,             // [2048][1024] bf16 out
                 u32* __restrict__ cnt,
                 const float* __restrict__ W1, u16* __restrict__ W1t,
                 const float* __restrict__ W2, u16* __restrict__ W2t) {
  __shared__ char hA[32 * 1024];       // LSTM: staged h(s). Transpose: 2 tile bufs.

  if (blockIdx.x >= 32) {
    // ---- W1/W2 transpose: 2 tiles per 512-thread block ----
    int tt2 = (blockIdx.x - 32) * 2 + (threadIdx.x >> 8);   // 0..33023
    const float* W; u16* Wt; int K, N, tt;
    if (tt2 < 1024) { W = W1; Wt = W1t; K = 1024; N = 1024;  tt = tt2; }
    else            { W = W2; Wt = W2t; K = 1024; N = 32000; tt = tt2 - 1024; }
    int ntn = N >> 5;
    int tn = tt % ntn, tk = tt / ntn;
    int n0 = tn << 5, k0 = tk << 5;
    float (*t)[33] = (float(*)[33])(hA + (threadIdx.x >> 8) * 4352);
    int t256 = threadIdx.x & 255;
    int tx = t256 & 31, ty = t256 >> 5;  // ty 0..7
#pragma unroll
    for (int j = 0; j < 4; ++j) {
      int k = ty * 4 + j;
      t[k][tx] = W[(size_t)(k0 + k) * N + n0 + tx];
    }
    __syncthreads();
#pragma unroll
    for (int j = 0; j < 4; ++j) {
      int n = ty * 4 + j;
      Wt[(size_t)(n0 + n) * K + k0 + tx] = f2bf(t[tx][n]);
    }
    return;
  }

  const int wg = blockIdx.x;           // 0..31
  const int u0 = wg << 5;              // 32 units per WG
  const int tid = threadIdx.x;
  const int lane = tid & 63;
  const int wv = tid >> 6;             // 0..7
  const int ln = lane & 15, khq = lane >> 4;

  const int g = ln & 3;                // gate index (i,f,cc,o)
  const int unit = u0 + wv * 4 + (ln >> 2);

  // ---- Wh preload: 32 x 16B via inline asm ----
  u32x4 bWq[32];
  {
    const u16* wrow = Wht + (size_t)(g * 1024 + unit) * 1024 + khq * 8;
#pragma unroll
    for (int kt = 0; kt < 32; ++kt) {
      const u16* pp = wrow + kt * 32;
      asm volatile("global_load_dwordx4 %0, %1, off" : "=v"(bWq[kt]) : "v"(pp));
    }
    asm volatile("s_waitcnt vmcnt(0)" ::: "memory");
  }

  // per-lane state (g==0 lanes meaningful after shfl combine)
  float cellR[4], holdR[4], xgr[4];
  u64 mA[4], mB[4];
  const float bn_s = gamma[unit] * rsqrtf(mvar[unit] + 1e-3f);
  const float bn_b = beta[unit] - mmean[unit] * bn_s;
  const size_t bstride = (size_t)128 * 4096;
  const float* xbase = xg + (size_t)(khq * 4) * bstride + g * 1024 + unit;
#pragma unroll
  for (int r = 0; r < 4; ++r) {
    int batch = khq * 4 + r;
    cellR[r] = encc[batch * 1024 + unit];
    holdR[r] = ench[batch * 1024 + unit];
    mA[r] = maskb[batch * 2];
    mB[r] = maskb[batch * 2 + 1];
  }
  // initial publish of h(0) into parity-0 buffer
#pragma unroll
  for (int r = 0; r < 4; ++r) {
    u32 w = (u32)f2bf(holdR[r]);
    u32 pw = (u32)__shfl_xor((int)w, 4);   // partner unit+1, same gate
    if ((ln & 7) == 0) {
      int batch = khq * 4 + r;
      AT_ST((u32*)((char*)hbuf32 + batch * 2048 + unit * 2), (w & 0xFFFFu) | (pw << 16));
    }
  }
#pragma unroll
  for (int r = 0; r < 4; ++r) xgr[r] = xbase[r * bstride];   // xg(0) prefetch
  asm volatile("s_waitcnt vmcnt(0)" ::: "memory");
  __syncthreads();
  if (tid == 0) {
    u32 oldv = AT_FAA(cnt);
    if (oldv != 31u) {
      int c = 0;
      while (AT_LD((const u32*)cnt) < 32u) {
        __builtin_amdgcn_s_sleep(1);
        if (++c > (1 << 18)) break;
      }
    }
  }
  __syncthreads();

  for (int s = 0; s < 128; ++s) {
    // ---- stage h(s): 8 back-to-back uncached u64 loads, one waitcnt ----
    u64 st[8];
    {
      const u64* base = (const u64*)((const char*)hbuf32 + (s & 1) * 32768) + tid;
#pragma unroll
      for (int k = 0; k < 8; ++k) {
        const u64* pp = base + k * 512;
        asm volatile("global_load_dwordx2 %0, %1, off sc0 sc1" : "=v"(st[k]) : "v"(pp));
      }
      asm volatile("s_waitcnt vmcnt(0)" ::: "memory");
      __builtin_amdgcn_sched_barrier(0);
#pragma unroll
      for (int k = 0; k < 8; ++k)
        *(u64*)(hA + swzB((tid + k * 512) * 8)) = st[k];
    }
    __syncthreads();                           // (A) hA ready

    // ---- 32 MFMA over full K, 2 chains; A from LDS ----
    f32x4 acc0 = {0.f, 0.f, 0.f, 0.f};
    f32x4 acc1 = {0.f, 0.f, 0.f, 0.f};
#pragma unroll
    for (int kt = 0; kt < 32; kt += 2) {
      s16x8 a0 = *(const s16x8*)(hA + swzB(ln * 2048 + kt * 64 + khq * 16));
      acc0 = __builtin_amdgcn_mfma_f32_16x16x32_bf16(
          a0, __builtin_bit_cast(s16x8, bWq[kt]), acc0, 0, 0, 0);
      s16x8 a1 = *(const s16x8*)(hA + swzB(ln * 2048 + (kt + 1) * 64 + khq * 16));
      acc1 = __builtin_amdgcn_mfma_f32_16x16x32_bf16(
          a1, __builtin_bit_cast(s16x8, bWq[kt + 1]), acc1, 0, 0, 0);
    }
    f32x4 accs = acc0 + acc1;

    // ---- gates fully in-wave (lane quads hold i,f,cc,o) + publish ----
    u32 bnpair[4];
    {
      u16 hbb[4], hbnb[4];
#pragma unroll
      for (int r = 0; r < 4; ++r) {
        float z = accs[r] + xgr[r];
        float sig = 1.f / (1.f + __expf(-z));
        float val = (g == 2) ? fmaxf(z, 0.f) : sig;
        float v1 = __shfl_xor(val, 1);
        float v2 = __shfl_xor(val, 2);
        float v3 = __shfl_xor(val, 3);
        float cnew = v1 * cellR[r] + val * v2;   // f*c + i*cc (g==0 view)
        float hnew = v3 * fmaxf(cnew, 0.f);
        u64 mm = (s < 64) ? mA[r] : mB[r];
        if (!((mm >> (s & 63)) & 1)) { cnew = cellR[r]; hnew = holdR[r]; }
        cellR[r] = cnew;
        holdR[r] = hnew;
        hbb[r] = f2bf(hnew);
        hbnb[r] = f2bf(hnew * bn_s + bn_b);
      }
#pragma unroll
      for (int r = 0; r < 4; ++r) {
        u32 w = (u32)hbb[r] | ((u32)hbnb[r] << 16);
        u32 pw = (u32)__shfl_xor((int)w, 4);
        u32 hpair = (w & 0xFFFFu) | ((pw & 0xFFFFu) << 16);
        bnpair[r] = (w >> 16) | (pw & 0xFFFF0000u);
        if (s < 127 && (ln & 7) == 0) {
          int batch = khq * 4 + r;
          AT_ST((u32*)((char*)hbuf32 + ((s + 1) & 1) * 32768 + batch * 2048 + unit * 2), hpair);
        }
      }
    }

    if (s < 127) {
      asm volatile("s_waitcnt vmcnt(0)" ::: "memory");   // drain h publishes
      __syncthreads();                         // (B) all publishes complete
      u32 oldv = 0xFFFFFFFFu;
      if (tid == 0) oldv = AT_FAA(cnt);
      // deferred hbn stores + xg(s+1) prefetch overlap the poll
      if ((ln & 7) == 0) {
#pragma unroll
        for (int r = 0; r < 4; ++r) {
          int batch = khq * 4 + r;
          *(u32*)((char*)hbn + (size_t)(batch * 128 + s) * 2048 + unit * 2) = bnpair[r];
        }
      }
      {
        const float* xb = xbase + (size_t)(s + 1) * 4096;
#pragma unroll
        for (int r = 0; r < 4; ++r) xgr[r] = xb[r * bstride];
      }
      if (tid == 0) {
        const u32 target = (u32)(s + 2) * 32u;
        if (oldv != target - 1u) {
          int c = 0;
          while (AT_LD((const u32*)cnt) < target) {
            __builtin_amdgcn_s_sleep(1);
            if (++c > (1 << 18)) break;
          }
        }
      }
      __syncthreads();                         // (C) release
    } else if ((ln & 7) == 0) {
      // s == 127: final hbn stores
#pragma unroll
      for (int r = 0; r < 4; ++r) {
        int batch = khq * 4 + r;
        *(u32*)((char*)hbn + (size_t)(batch * 128 + s) * 2048 + unit * 2) = bnpair[r];
      }
    }
  }
}

// ---------- softmax finish ----------

// f32 path (fallback): in-place scale of f32 exp
__global__ void scale_kernel(float* __restrict__ out, const float* __restrict__ rs) {
  const int total4 = 16384000;              // 65,536,000 / 4
  for (int i = blockIdx.x * 256 + threadIdx.x; i < total4; i += gridDim.x * 256) {
    float4* p = (float4*)out + i;
    float4 v = *p;
    int row = i / 8000;                     // 8000 float4 per row
    float sF = 1.0f / rs[row];
    v.x *= sF; v.y *= sF; v.z *= sF; v.w *= sF;
    *p = v;
  }
}

// bf16 path: one row per block (2048 blocks) — no division, coalesced.
__global__ __launch_bounds__(256)
void scale_bf_kernel(float* __restrict__ out, const u16* __restrict__ e,
                     const float* __restrict__ rs) {
  const int row = blockIdx.x;               // 0..2047
  const float sF = 1.0f / rs[row];
  const s16x8* src = (const s16x8*)(e + (size_t)row * 32000);
  float4* dst = (float4*)(out + (size_t)row * 32000);
  for (int i = threadIdx.x; i < 4000; i += 256) {
    s16x8 v = src[i];
    float4 o0, o1;
    o0.x = bf2f((u16)v[0]) * sF; o0.y = bf2f((u16)v[1]) * sF;
    o0.z = bf2f((u16)v[2]) * sF; o0.w = bf2f((u16)v[3]) * sF;
    o1.x = bf2f((u16)v[4]) * sF; o1.y = bf2f((u16)v[5]) * sF;
    o1.z = bf2f((u16)v[6]) * sF; o1.w = bf2f((u16)v[7]) * sF;
    dst[2 * i] = o0;
    dst[2 * i + 1] = o1;
  }
}

// ---------- launch ----------

extern "C" void kernel_launch(void* const* d_in, const int* in_sizes, int n_in,
                              void* d_out, int out_size, void* d_ws, size_t ws_size,
                              hipStream_t stream) {
  (void)in_sizes; (void)n_in; (void)out_size;
  const int*   inputs = (const int*)d_in[0];
  const float* ench   = (const float*)d_in[1];
  const float* encc   = (const float*)d_in[2];
  const float* emb    = (const float*)d_in[3];
  const float* Wx     = (const float*)d_in[4];
  const float* Wh     = (const float*)d_in[5];
  const float* bb     = (const float*)d_in[6];
  const float* gamma  = (const float*)d_in[7];
  const float* beta   = (const float*)d_in[8];
  const float* mmean  = (const float*)d_in[9];
  const float* mvar   = (const float*)d_in[10];
  const float* W1     = (const float*)d_in[11];
  const float* b1     = (const float*)d_in[12];
  const float* W2     = (const float*)d_in[13];
  const float* b2     = (const float*)d_in[14];
  float* out = (float*)d_out;

  char* p = (char*)d_ws;
  u32*   cnt    = (u32*)(p + 0);            // word 0
  float* rowsum = (float*)(p + 1024);       // 2048 floats; memset covers [0,9216)
  u64*   maskb  = (u64*)(p + 10240);        // 256B, written by prepass
  u32*   hbuf32 = (u32*)(p + 16384);        // 64KB (2 x 32KB parity tiles)
  size_t off = 81920;
  u16*   xbf  = (u16*)(p + off);     off += (size_t)2048 * 512 * 2;     // 2MB
  u16*   Wxt  = (u16*)(p + off);     off += (size_t)4096 * 512 * 2;     // 4MB
  u16*   Wht  = (u16*)(p + off);     off += (size_t)4096 * 1024 * 2;    // 8MB
  u16*   W1t  = (u16*)(p + off);     off += (size_t)1024 * 1024 * 2;    // 2MB
  u16*   W2t  = (u16*)(p + off);     off += (size_t)32000 * 1024 * 2;   // 64MB
  float* xg   = (float*)(p + off);   off += (size_t)2048 * 4096 * 4;    // 32MB
  u16*   hbn  = (u16*)(p + off);     off += (size_t)2048 * 1024 * 2;    // 4MB
  u16*   d1   = (u16*)(p + off);     off += (size_t)2048 * 1024 * 2;    // 4MB
  size_t off_base = off;
  u16*   expbf = (u16*)(p + off);    off += (size_t)2048 * 32000 * 2;   // 125MB (optional)
  if (ws_size < off_base) return;  // insufficient scratch; avoid OOB
  const bool bf16path = (ws_size >= off);

  hipMemsetAsync(d_ws, 0, 9216, stream);  // cnt + rowsum

  // pre-pass: embed (512) + Wx (2048) + Wh (4096) transposes + mask (1)
  prepass_kernel<<<6657, 256, 0, stream>>>(inputs, emb, xbf, Wx, Wxt, Wh, Wht, maskb);

  gemm_bf16<0><<<16 * 32, 256, 0, stream>>>(xbf, Wxt, bb, xg, nullptr, 2048, 4096, 512);

  // LSTM (32 persistent blocks) + W1/W2 transposes (16512 blocks on idle CUs)
  lstm_kernel<<<32 + 16512, 512, 0, stream>>>(xg, Wht, maskb, ench, encc, gamma, beta,
                                              mmean, mvar, hbuf32, hbn, cnt,
                                              W1, W1t, W2, W2t);

  gemm_bf16<1><<<16 * 8, 256, 0, stream>>>(hbn, W1t, b1, d1, nullptr, 2048, 1024, 1024);

  if (bf16path) {
    gemm256_exp<<<8 * 125, 512, 0, stream>>>(d1, W2t, b2, expbf, rowsum, 2048, 32000, 1024);
    scale_bf_kernel<<<2048, 256, 0, stream>>>(out, expbf, rowsum);
  } else {
    gemm_bf16<2><<<16 * 250, 256, 0, stream>>>(d1, W2t, b2, out, rowsum, 2048, 32000, 1024);
    scale_kernel<<<2048, 256, 0, stream>>>(out, rowsum);
  }
}